// Round 2
// baseline (576.344 us; speedup 1.0000x reference)
//
#include <hip/hip_runtime.h>
#include <cmath>

#define N_AG 2048
#define HID  2048
#define OBSD 1024
#define ACT  64
#define GATES (4*HID)   // 8192

typedef short s16x8 __attribute__((ext_vector_type(8)));
typedef short s16x4 __attribute__((ext_vector_type(4)));
typedef float f32x4 __attribute__((ext_vector_type(4)));

__device__ __forceinline__ unsigned short f2bf(float f) {
  union { float f; unsigned u; } v; v.f = f;
  return (unsigned short)((v.u + 0x7FFFu + ((v.u >> 16) & 1u)) >> 16);
}
__device__ __forceinline__ float bf2f(unsigned short u) {
  union { float f; unsigned u; } v; v.u = ((unsigned)u) << 16;
  return v.f;
}
__device__ __forceinline__ float sigm(float x) { return 1.0f / (1.0f + expf(-x)); }

// async global->LDS DMA, 16B per lane; LDS dest = wave-uniform base + lane*16
__device__ __forceinline__ void gload16(const unsigned short* g, unsigned short* l) {
  __builtin_amdgcn_global_load_lds(
      (const __attribute__((address_space(1))) void*)g,
      (__attribute__((address_space(3))) void*)l, 16, 0, 0);
}

// =====================================================================================
// 256x256 bf16 GEMM, 4-phase K-tile with ONE-PHASE READ-AHEAD (ds_read || MFMA overlap).
// C(MxN) = A(MxK,row) * B(NxK,row)^T, bf16 out. 512 thr = 8 waves (2M x 4N),
// per-wave out 128x64, BK=64, LDS 128 KiB double-buffered, 1 block/CU.
//
// R1 post-mortem: [reads][bar][lgkm0][MFMA][bar] serializes LDS drain (750cyc/tile)
// with MFMA (614cyc/tile) -> 38.5% MfmaUtil. Fix: phase p issues frags(p+1); MFMA(p)
// consumes frags issued in phase p-1 (compiler emits counted lgkm from real deps).
// Read windows: ph4(t-1):{af0,bA}  ph1:{bB}  ph2:{af1}  ph3:{}  -- each frag set is
// consumed in <=2 consecutive phases and rewritten 2 phases after last use, so ONE
// register set each suffices (no dbuf): af0/af1 = 32+32, bA/bB = 16+16 VGPR.
//
// Hazard ledger (all verified):
//  ST-after-read: every ST's target region has its reads lgkm-waited before the
//   consuming MFMA, which is >=1 barrier before the ST issue.
//  DMA-before-read: bB@ph1 <- staged t-2.ph4: drained by vmcnt(2)@ph4(t-1)+bar;
//   af1@ph2 <- t-1.ph1: same; {af0,bA}@ph4 <- t-1.{ph3,ph2}: drained by
//   vmcnt(2)@ph4(t-1)+bar (vmcnt leaves only t-1.ph4's own 2 loads, for B_{t+1}).
//   t=0/1 specials covered by prologue vmcnt(0)+bar (stages tile0 full + tile1 h0-h2).
// Swizzle unchanged from R1 (bank-conflict == 0): LDS 16B slot ^= (row&7), applied as
// pre-swizzled GLOBAL source col (gload_lds writes linearly) + same XOR on ds_read col.
// =====================================================================================
__global__ __launch_bounds__(512, 2) void gemm256(
    const unsigned short* __restrict__ A, const unsigned short* __restrict__ B,
    int K, int lda, int ldb, unsigned short* __restrict__ C, int ldc)
{
  __shared__ __align__(16) unsigned short As[32768];  // 64 KiB
  __shared__ __align__(16) unsigned short Bs[32768];  // 64 KiB

  const int tid  = threadIdx.x;
  const int lane = tid & 63;
  const int wave = tid >> 6;                 // 0..7
  const int wm   = wave >> 2, wn = wave & 3; // 2M x 4N wave grid
  const int quad = lane >> 4, l16 = lane & 15, r7 = lane & 7;
  const long tileM = (long)blockIdx.y * 256;
  const long tileN = (long)blockIdx.x * 256;

  // staging: per-lane offset (1 VGPR each); uniform (c,h,t) parts fold into SGPR base.
  // col pre-swizzled: global col-block (lane&7)^(lane>>3) -> LDS slot (lane&7)=g^(row&7)
  const unsigned scol  = (((lane & 7) ^ (lane >> 3)) * 8u);
  const unsigned aoffL = (unsigned)(tileM + wave * 8 + (lane >> 3)) * (unsigned)lda + scol;
  const unsigned boffL = (unsigned)(tileN + (wave >> 2) * 64 + (wave & 3) * 8 + (lane >> 3))
                           * (unsigned)ldb + scol;

#define ST_A(d, h, t) { \
    gload16(A + aoffL + (unsigned)((h) * 64) * (unsigned)lda + (unsigned)(t) * 64u, \
            &As[(d) * 16384 + (h) * 8192 + wave * 512]); \
    gload16(A + aoffL + (unsigned)(128 + (h) * 64) * (unsigned)lda + (unsigned)(t) * 64u, \
            &As[(d) * 16384 + (h) * 8192 + wave * 512 + 4096]); }
#define ST_B(d, h, t) { \
    gload16(B + boffL + (unsigned)((h) * 32) * (unsigned)ldb + (unsigned)(t) * 64u, \
            &Bs[(d) * 16384 + (h) * 8192 + wave * 512]); \
    gload16(B + boffL + (unsigned)(128 + (h) * 32) * (unsigned)ldb + (unsigned)(t) * 64u, \
            &Bs[(d) * 16384 + (h) * 8192 + wave * 512 + 4096]); }

  const int ax = wm * 4096 + l16 * 64;       // within A half region (elems)
  const int bx = wn * 2048 + l16 * 64;       // within B half region
  const int c0 = (quad ^ r7) * 8;            // swizzled col, K-step 0
  const int c1 = ((4 + quad) ^ r7) * 8;      // swizzled col, K-step 1

  s16x8 af0[4][2], af1[4][2], bA[2][2], bB[2][2];
  f32x4 acc[8][4] = {};

#define LD_A(d, Mh, dst) { const unsigned short* p_ = &As[(d) * 16384 + (Mh) * 8192 + ax]; \
    _Pragma("unroll") for (int ml = 0; ml < 4; ++ml) { \
      dst[ml][0] = *(const s16x8*)(p_ + ml * 1024 + c0); \
      dst[ml][1] = *(const s16x8*)(p_ + ml * 1024 + c1); } }
#define LD_B(d, Nh, dst) { const unsigned short* p_ = &Bs[(d) * 16384 + (Nh) * 8192 + bx]; \
    _Pragma("unroll") for (int nl = 0; nl < 2; ++nl) { \
      dst[nl][0] = *(const s16x8*)(p_ + nl * 1024 + c0); \
      dst[nl][1] = *(const s16x8*)(p_ + nl * 1024 + c1); } }
#define QMM(Mh, Nh, afv, bb) \
    _Pragma("unroll") for (int ml = 0; ml < 4; ++ml) \
    _Pragma("unroll") for (int nl = 0; nl < 2; ++nl) \
    _Pragma("unroll") for (int ks = 0; ks < 2; ++ks) \
      acc[(Mh) * 4 + ml][(Nh) * 2 + nl] = __builtin_amdgcn_mfma_f32_16x16x32_bf16( \
          afv[ml][ks], bb[nl][ks], acc[(Mh) * 4 + ml][(Nh) * 2 + nl], 0, 0, 0);
#define BAR __builtin_amdgcn_s_barrier()

  const int NT = K >> 6;   // K-tiles of 64; requires NT >= 3 (K=2048 -> 32)

  // prologue: tile0 {h0..h3} + tile1 {h0,h1,h2}; drain ALL (covers t=0/1 read windows)
  ST_B(0, 0, 0); ST_A(0, 0, 0); ST_B(0, 1, 0); ST_A(0, 1, 0);
  ST_B(1, 0, 1); ST_A(1, 0, 1); ST_B(1, 1, 1);
  asm volatile("s_waitcnt vmcnt(0)" ::: "memory");
  BAR;
  LD_A(0, 0, af0); LD_B(0, 0, bA);   // frags for t=0 ph1

  for (int t = 0; t < NT; ++t) {
    const int cur = t & 1, nxt = cur ^ 1;
    const bool s1 = (t + 1 < NT), s2 = (t + 2 < NT);
    // ---- ph1: read bB (for ph2); stage (t+1).A-Mh1 -> nxt; MFMA Q(Mh0,Nh0)
    LD_B(cur, 1, bB);
    if (s1) ST_A(nxt, 1, t + 1);
    __builtin_amdgcn_s_setprio(1); QMM(0, 0, af0, bA); __builtin_amdgcn_s_setprio(0);
    BAR;
    // ---- ph2: read af1 (for ph3); stage (t+2).B-Nh0 -> cur; MFMA Q(Mh0,Nh1)
    LD_A(cur, 1, af1);
    if (s2) ST_B(cur, 0, t + 2);
    __builtin_amdgcn_s_setprio(1); QMM(0, 1, af0, bB); __builtin_amdgcn_s_setprio(0);
    BAR;
    // ---- ph3: no reads; stage (t+2).A-Mh0 -> cur; MFMA Q(Mh1,Nh0)
    if (s2) ST_A(cur, 0, t + 2);
    __builtin_amdgcn_s_setprio(1); QMM(1, 0, af1, bA); __builtin_amdgcn_s_setprio(0);
    BAR;
    // ---- ph4: stage (t+2).B-Nh1 -> cur; read next tile's {af0,bA}; MFMA Q(Mh1,Nh1)
    if (s2) ST_B(cur, 1, t + 2);
    if (s1) { LD_A(nxt, 0, af0); LD_B(nxt, 0, bA); }
    __builtin_amdgcn_s_setprio(1); QMM(1, 1, af1, bB); __builtin_amdgcn_s_setprio(0);
    asm volatile("s_waitcnt vmcnt(2)" ::: "memory");  // all staging for t+1 landed
    BAR;
  }

  // epilogue: C/D layout col=l16, row=quad*4+reg (verified m89/m91)
#pragma unroll
  for (int mf = 0; mf < 8; ++mf) {
    long r0 = tileM + wm * 128 + mf * 16 + quad * 4;
#pragma unroll
    for (int nf = 0; nf < 4; ++nf) {
      long col = tileN + wn * 64 + nf * 16 + l16;
#pragma unroll
      for (int r = 0; r < 4; ++r)
        C[(r0 + r) * ldc + col] = f2bf(acc[mf][nf][r]);
    }
  }
#undef ST_A
#undef ST_B
#undef LD_A
#undef LD_B
#undef QMM
#undef BAR
}

// ---------------- bf16 MFMA GEMM, dbuf global_load_lds pipeline (one barrier/K-iter).
// Retained for small-grid shapes (encoder N=2048: 256 blocks; head N=128).
// C(MxN) = A(MxK,row) * B(NxK,row)^T.  grid x = B-tiles, y = A-tiles.
// MODE 1: bf16(tanh(acc+bias[col])) (encoder). MODE 2: f32 store (head).
template <int MODE>
__global__ __launch_bounds__(256, 4) void gemm_bt(
    const unsigned short* __restrict__ A, const unsigned short* __restrict__ B,
    int K, int lda, int ldb,
    unsigned short* __restrict__ Cb, float* __restrict__ Cf, int ldc,
    const float* __restrict__ bias)
{
  __shared__ __align__(16) unsigned short As0[2 * 128 * 32];
  __shared__ __align__(16) unsigned short Bs0[2 * 128 * 32];
  const int tid  = threadIdx.x;
  const int lane = tid & 63;
  const int wave = tid >> 6;
  const int wm = wave >> 1, wn = wave & 1;
  const int quad = lane >> 4, l16 = lane & 15;
  const long tileM = (long)blockIdx.y * 128;
  const long tileN = (long)blockIdx.x * 128;

  const int srow = lane >> 2;
  const int skc  = (lane & 3) * 8;
  const unsigned short* gA = &A[(tileM + wave * 32 + srow) * lda + skc];
  const unsigned short* gB = &B[(tileN + wave * 32 + srow) * ldb + skc];
  const int ldsOff = wave * 32 * 32;

  f32x4 acc[4][4] = {};
  const int nIt = K >> 5;

  gload16(gA, &As0[ldsOff]);
  gload16(gA + 16 * lda, &As0[ldsOff + 16 * 32]);
  gload16(gB, &Bs0[ldsOff]);
  gload16(gB + 16 * ldb, &Bs0[ldsOff + 16 * 32]);

  for (int i = 0; i < nIt; ++i) {
    __syncthreads();  // drains DMA(tile i) issued one MFMA-phase earlier
    const int cb = (i & 1) * 4096;
    if (i + 1 < nIt) {
      const int nb = ((i + 1) & 1) * 4096;
      const long ko = (long)(i + 1) * 32;
      gload16(gA + ko, &As0[nb + ldsOff]);
      gload16(gA + ko + 16 * lda, &As0[nb + ldsOff + 16 * 32]);
      gload16(gB + ko, &Bs0[nb + ldsOff]);
      gload16(gB + ko + 16 * ldb, &Bs0[nb + ldsOff + 16 * 32]);
    }
    s16x8 af[4], bfr[4];
#pragma unroll
    for (int ii = 0; ii < 4; ++ii)
      af[ii] = *(const s16x8*)&As0[cb + (wm * 64 + ii * 16 + l16) * 32 + quad * 8];
#pragma unroll
    for (int j = 0; j < 4; ++j)
      bfr[j] = *(const s16x8*)&Bs0[cb + (wn * 64 + j * 16 + l16) * 32 + quad * 8];
#pragma unroll
    for (int ii = 0; ii < 4; ++ii)
#pragma unroll
      for (int j = 0; j < 4; ++j)
        acc[ii][j] = __builtin_amdgcn_mfma_f32_16x16x32_bf16(af[ii], bfr[j], acc[ii][j], 0, 0, 0);
  }

  // C/D layout: col=lane&15, row=quad*4+reg  [verified m89/m91]
#pragma unroll
  for (int i = 0; i < 4; ++i) {
    long r0 = tileM + wm * 64 + i * 16 + quad * 4;
#pragma unroll
    for (int j = 0; j < 4; ++j) {
      long col = tileN + wn * 64 + j * 16 + l16;
      float bv = (MODE == 1) ? bias[col] : 0.f;
#pragma unroll
      for (int r = 0; r < 4; ++r) {
        float v = acc[i][j][r];
        if (MODE == 1) v = tanhf(v + bv);
        if (MODE == 2) Cf[(r0 + r) * ldc + col] = v;
        else           Cb[(r0 + r) * ldc + col] = f2bf(v);
      }
    }
  }
}

// ---------------- f32 -> bf16 convert, two equal-size arrays in one dispatch
__global__ void cvt4_dual(const float* __restrict__ inA, unsigned short* __restrict__ outA,
                          const float* __restrict__ inB, unsigned short* __restrict__ outB) {
  int i = blockIdx.x * 256 + threadIdx.x;  // over 512K chunks each
  f32x4 a = ((const f32x4*)inA)[i];
  f32x4 b = ((const f32x4*)inB)[i];
  s16x4 oa, ob;
#pragma unroll
  for (int c = 0; c < 4; ++c) { oa[c] = (short)f2bf(a[c]); ob[c] = (short)f2bf(b[c]); }
  ((s16x4*)outA)[i] = oa;
  ((s16x4*)outB)[i] = ob;
}

// ---------------- weights: Wihb = bf16(w_ih); W2b = bf16(w_hh - s*w_ih), s=1/(nA-1)
// (folds the -s*h@Wih^T comm term into the recurrent weight; exact for alive==1)
__global__ void buildw(const float* __restrict__ w_ih, const float* __restrict__ w_hh,
                       const float* __restrict__ nA,
                       unsigned short* __restrict__ Wihb, unsigned short* __restrict__ W2b) {
  int i = blockIdx.x * 256 + threadIdx.x;  // over GATES*HID/4 = 4M chunks
  float s = 1.0f / (nA[0] - 1.0f);
  size_t off = (size_t)i * 4;
  f32x4 a = *(const f32x4*)&w_ih[off];
  f32x4 b = *(const f32x4*)&w_hh[off];
  s16x4 oa, ob;
#pragma unroll
  for (int c = 0; c < 4; ++c) {
    oa[c] = (short)f2bf(a[c]);
    ob[c] = (short)f2bf(b[c] - s * a[c]);
  }
  *(s16x4*)&Wihb[off] = oa;
  *(s16x4*)&W2b[off] = ob;
}

// ---------------- head weights: Whd row 0..63 = act_w, 64 = val_w, 65..127 = 0
__global__ void build_whd(const float* __restrict__ act_w, const float* __restrict__ val_w,
                          unsigned short* __restrict__ whd) {
  int i = blockIdx.x * 256 + threadIdx.x;  // over 128*HID/4 = 64K chunks
  int r = i >> 9;
  int k = (i & 511) * 4;
  f32x4 v = {0.f, 0.f, 0.f, 0.f};
  if (r < 64)       v = *(const f32x4*)&act_w[(size_t)r * HID + k];
  else if (r == 64) v = *(const f32x4*)&val_w[k];
  s16x4 o;
  o[0] = (short)f2bf(v[0]); o[1] = (short)f2bf(v[1]);
  o[2] = (short)f2bf(v[2]); o[3] = (short)f2bf(v[3]);
  *(s16x4*)&whd[(size_t)r * HID + k] = o;
}

// ---------------- combined bias (plain order): bc[g] = b_ih[g] + b_hh[g]
__global__ void biasmix(const float* __restrict__ b_ih, const float* __restrict__ b_hh,
                        float* __restrict__ bc) {
  int i = blockIdx.x * 256 + threadIdx.x;
  if (i < GATES) bc[i] = b_ih[i] + b_hh[i];
}

// ---------------- n_alive reduction
__global__ void nalive_k(const float* __restrict__ alive, float* __restrict__ nA) {
  __shared__ float red[256];
  float s = 0.f;
  for (int i = threadIdx.x; i < N_AG; i += 256) s += alive[i];
  red[threadIdx.x] = s;
  __syncthreads();
  for (int st = 128; st > 0; st >>= 1) {
    if (threadIdx.x < st) red[threadIdx.x] += red[threadIdx.x + st];
    __syncthreads();
  }
  if (threadIdx.x == 0) nA[0] = red[0];
}

// ---------------- column sum over bf16 h: S[hid] += sum_n alive[n]*h[n][hid]
__global__ void colsum(const unsigned short* __restrict__ hb, const float* __restrict__ alive,
                       float* __restrict__ S) {
  int hid = blockIdx.x * 256 + threadIdx.x;
  int r0 = blockIdx.y * 128;
  float s = 0.f;
  for (int n = r0; n < r0 + 128; ++n) s += alive[n] * bf2f(hb[(size_t)n * HID + hid]);
  atomicAdd(&S[hid], s);
}

// ---------------- GEMV: q[g] = s * sum_k Wihb[g][k] * S[k]
__global__ __launch_bounds__(256) void gemv_q(const unsigned short* __restrict__ Wihb,
                                              const float* __restrict__ S,
                                              const float* __restrict__ nA,
                                              float* __restrict__ q) {
  __shared__ float Sl[HID];
  int tid = threadIdx.x, lane = tid & 63, wave = tid >> 6;
  for (int k = tid; k < HID; k += 256) Sl[k] = S[k];
  __syncthreads();
  int g = blockIdx.x * 4 + wave;
  const unsigned short* wr = Wihb + (size_t)g * HID;
  float acc = 0.f;
#pragma unroll
  for (int c = 0; c < 4; ++c) {
    int k = c * 512 + lane * 8;
    s16x8 w = *(const s16x8*)&wr[k];
#pragma unroll
    for (int e = 0; e < 8; ++e) acc += bf2f((unsigned short)w[e]) * Sl[k + e];
  }
  for (int off = 32; off; off >>= 1) acc += __shfl_xor(acc, off);
  if (lane == 0) q[g] = acc / (nA[0] - 1.0f);
}

// ---------------- LSTM pointwise: z = E1 (+ z2 + q if !first) + bc; gate order i,f,g,o
__global__ void lstm_k(const unsigned short* __restrict__ zb, const unsigned short* __restrict__ E1b,
                       const float* __restrict__ q, const float* __restrict__ bc,
                       float* __restrict__ cell, unsigned short* __restrict__ hb, int first) {
  int i = blockIdx.x * 256 + threadIdx.x;  // over N_AG*HID/4 = 1M
  int n = i >> 9;
  int hid = (i & 511) * 4;
  size_t base = (size_t)n * GATES;
  float zt[4][4];
#pragma unroll
  for (int t = 0; t < 4; ++t) {
    int off = t * HID + hid;
    s16x4 e1 = *(const s16x4*)&E1b[base + off];
    f32x4 bcv = *(const f32x4*)&bc[off];
#pragma unroll
    for (int c = 0; c < 4; ++c) zt[t][c] = bf2f((unsigned short)e1[c]) + bcv[c];
    if (!first) {
      s16x4 z2 = *(const s16x4*)&zb[base + off];
      f32x4 qv = *(const f32x4*)&q[off];
#pragma unroll
      for (int c = 0; c < 4; ++c) zt[t][c] += bf2f((unsigned short)z2[c]) + qv[c];
    }
  }
  f32x4 cold = {0.f, 0.f, 0.f, 0.f};
  if (!first) cold = ((const f32x4*)cell)[i];
  f32x4 cnew; s16x4 xb;
#pragma unroll
  for (int c = 0; c < 4; ++c) {
    float ig = sigm(zt[0][c]);
    float fg = sigm(zt[1][c]);
    float gg = tanhf(zt[2][c]);
    float og = sigm(zt[3][c]);
    cnew[c] = fg * cold[c] + ig * gg;
    float hv = og * tanhf(cnew[c]);
    xb[c] = (short)f2bf(hv);
  }
  ((f32x4*)cell)[i] = cnew;
  *(s16x4*)&hb[(size_t)n * HID + hid] = xb;
}

// ---------------- head epilogue: log_softmax over 64 logits + value; 1 wave/agent
__global__ __launch_bounds__(256) void head_ep(const float* __restrict__ zh,
                                               const float* __restrict__ act_b,
                                               const float* __restrict__ val_b,
                                               float* __restrict__ out) {
  int wave = threadIdx.x >> 6, lane = threadIdx.x & 63;
  int row = blockIdx.x * 4 + wave;
  const float* zr = zh + (size_t)row * 128;
  float a = zr[lane] + act_b[lane];
  float m = a;
  for (int off = 32; off; off >>= 1) m = fmaxf(m, __shfl_xor(m, off));
  float ex = expf(a - m), s = ex;
  for (int off = 32; off; off >>= 1) s += __shfl_xor(s, off);
  out[(size_t)row * ACT + lane] = a - m - logf(s);
  if (lane == 0) out[(size_t)N_AG * ACT + row] = zr[64] + val_b[0];
}

extern "C" void kernel_launch(void* const* d_in, const int* in_sizes, int n_in,
                              void* d_out, int out_size, void* d_ws, size_t ws_size,
                              hipStream_t stream) {
  const float* obs   = (const float*)d_in[0];
  const float* alive = (const float*)d_in[1];
  const float* enc_w = (const float*)d_in[2];
  const float* enc_b = (const float*)d_in[3];
  // d_in[4] g_w, d_in[5] g_b unused: gate = ceil(sigmoid(.)) == 1 identically
  const float* w_ih  = (const float*)d_in[6];
  const float* w_hh  = (const float*)d_in[7];
  const float* b_ih  = (const float*)d_in[8];
  const float* b_hh  = (const float*)d_in[9];
  const float* act_w = (const float*)d_in[10];
  const float* act_b = (const float*)d_in[11];
  const float* val_w = (const float*)d_in[12];
  const float* val_b = (const float*)d_in[13];
  float* out = (float*)d_out;

  char* p = (char*)d_ws;
  unsigned short* Wihb = (unsigned short*)p; p += (size_t)GATES * HID * 2;  // 32 MB
  unsigned short* W2b  = (unsigned short*)p; p += (size_t)GATES * HID * 2;  // 32 MB
  unsigned short* E1b  = (unsigned short*)p; p += (size_t)N_AG * GATES * 2; // 32 MB
  unsigned short* zb   = (unsigned short*)p; p += (size_t)N_AG * GATES * 2; // 32 MB
  unsigned short* obsb = (unsigned short*)p; p += (size_t)N_AG * OBSD * 2;  // 4 MB
  unsigned short* encb = (unsigned short*)p; p += (size_t)HID * OBSD * 2;   // 4 MB
  unsigned short* eb   = (unsigned short*)p; p += (size_t)N_AG * HID * 2;   // 8 MB
  unsigned short* hb   = (unsigned short*)p; p += (size_t)N_AG * HID * 2;   // 8 MB
  unsigned short* Whd  = (unsigned short*)p; p += (size_t)128 * HID * 2;    // 512 KB
  float* cell = (float*)p; p += (size_t)N_AG * HID * 4;                     // 16 MB
  float* zh   = (float*)p; p += (size_t)N_AG * 128 * 4;                     // 1 MB
  float* bc   = (float*)p; p += GATES * 4;
  float* q    = (float*)p; p += GATES * 4;
  float* S    = (float*)p; p += HID * 4;
  float* nA   = (float*)p; p += 256;

  cvt4_dual<<<(N_AG * OBSD / 4) / 256, 256, 0, stream>>>(obs, obsb, enc_w, encb);
  nalive_k<<<1, 256, 0, stream>>>(alive, nA);
  buildw<<<((size_t)GATES * HID / 4) / 256, 256, 0, stream>>>(w_ih, w_hh, nA, Wihb, W2b);
  build_whd<<<(128 * HID / 4) / 256, 256, 0, stream>>>(act_w, val_w, Whd);
  biasmix<<<GATES / 256, 256, 0, stream>>>(b_ih, b_hh, bc);

  // encoder: eb = bf16(tanh(obs @ enc_w^T + enc_b))  (128^2 kernel: 256-block grid)
  gemm_bt<1><<<dim3(HID / 128, N_AG / 128), 256, 0, stream>>>(
      obsb, encb, OBSD, OBSD, OBSD, eb, nullptr, HID, enc_b);

  // E1 = e @ Wih^T (bf16) — doubles as z of iter 0 (h==0, c==0).  256^2 read-ahead kernel.
  gemm256<<<dim3(GATES / 256, N_AG / 256), 512, 0, stream>>>(
      eb, Wihb, HID, HID, HID, E1b, GATES);
  lstm_k<<<(N_AG * HID / 4) / 256, 256, 0, stream>>>(nullptr, E1b, nullptr, bc, cell, hb, 1);

  for (int it = 1; it < 3; ++it) {
    hipMemsetAsync(S, 0, HID * 4, stream);
    colsum<<<dim3(HID / 256, 16), 256, 0, stream>>>(hb, alive, S);
    gemv_q<<<GATES / 4, 256, 0, stream>>>(Wihb, S, nA, q);
    // z2 = h @ W2^T, K=2048 (comm -s*h@Wih folded into W2)
    gemm256<<<dim3(GATES / 256, N_AG / 256), 512, 0, stream>>>(
        hb, W2b, HID, HID, HID, zb, GATES);
    lstm_k<<<(N_AG * HID / 4) / 256, 256, 0, stream>>>(zb, E1b, q, bc, cell, hb, 0);
  }

  // head: zh(2048x128) = h @ Whd^T via MFMA, then log_softmax + value epilogue
  gemm_bt<2><<<dim3(1, N_AG / 128), 256, 0, stream>>>(
      hb, Whd, HID, HID, HID, nullptr, zh, 128, nullptr);
  head_ep<<<N_AG / 4, 256, 0, stream>>>(zh, act_b, val_b, out);
}

// Round 3
// 565.078 us; speedup vs baseline: 1.0199x; 1.0199x over previous
//
#include <hip/hip_runtime.h>
#include <cmath>

#define N_AG 2048
#define HID  2048
#define OBSD 1024
#define ACT  64
#define GATES (4*HID)   // 8192

typedef short s16x8 __attribute__((ext_vector_type(8)));
typedef short s16x4 __attribute__((ext_vector_type(4)));
typedef float f32x4 __attribute__((ext_vector_type(4)));

__device__ __forceinline__ unsigned short f2bf(float f) {
  union { float f; unsigned u; } v; v.f = f;
  return (unsigned short)((v.u + 0x7FFFu + ((v.u >> 16) & 1u)) >> 16);
}
__device__ __forceinline__ float bf2f(unsigned short u) {
  union { float f; unsigned u; } v; v.u = ((unsigned)u) << 16;
  return v.f;
}
__device__ __forceinline__ float sigm(float x) { return 1.0f / (1.0f + expf(-x)); }

// async global->LDS DMA, 16B per lane; LDS dest = wave-uniform base + lane*16
__device__ __forceinline__ void gload16(const unsigned short* g, unsigned short* l) {
  __builtin_amdgcn_global_load_lds(
      (const __attribute__((address_space(1))) void*)g,
      (__attribute__((address_space(3))) void*)l, 16, 0, 0);
}

// =====================================================================================
// 256x256 bf16 GEMM, 4-phase K-tile, read-ahead + sched_barrier-pinned overlap.
// C(MxN) = A(MxK,row) * B(NxK,row)^T, bf16 out. 512 thr = 8 waves (2M x 4N),
// per-wave out 128x64, BK=64, LDS 128 KiB double-buffered, 1 block/CU.
//
// R2 post-mortem: (a) vmcnt(2)@ph4 over-drained t+2 staging issued 1-2 phases prior
// (should leave it in flight); (b) nothing stopped the scheduler from sinking the
// read-ahead ds_reads below the MFMA cluster -> overlap never happened.
// R3: one-tile-ahead staging with a FIFO-verified counted-vmcnt ledger, and a
// sched_barrier(0) per phase pinning [LD/ST issue] before [MFMA] so the LDS drain
// runs under the matrix pipe. QMM ks-outermost (dependent acc MFMAs 8 apart).
//
// Per-tile schedule (cur = t&1, nxt = cur^1; tile t+1 staged into buf nxt):
//  ph1: rd bB(cur,Nh1) | ST B-Nh0,A-Mh0(t+1) | MFMA Q00(af0,bA) | vmcnt(4) [A-Mh1(t) rdy]
//  ph2: rd af1(cur,Mh1)| ST B-Nh1(t+1)       | MFMA Q01(af0,bB) | vmcnt(2) [B0/A0(t+1) rdy]
//  ph3:                | ST A-Mh1(t+1)       | MFMA Q10(af1,bA) | rd bA(nxt,Nh0) AFTER
//                                              MFMA (WAR: MFMA uses old bA regs)
//  ph4: rd af0(nxt,Mh0)|                     | MFMA Q11(af1,bB) | vmcnt(2) [B-Nh1(t+1) rdy]
// FIFO ledger (issue 4/2/2/0 per phase, steady state): ph1-end 6->vmcnt(4) drains
// ph3(t-1)'s 2; ph2-end 6->vmcnt(2) drains ph1's 4; ph4-end 4->vmcnt(2) drains ph2's 2.
// Tail t=NT-1: no ST; ph1 uses vmcnt(0); other drains skipped. Each drain precedes the
// barrier before any wave reads the region (DMA completion is per-wave; barrier fans it out).
// ST-after-read: every overwritten region's last ds_read was >=4 phases (w/ barriers) prior.
// Swizzle unchanged (bank-conflict == 0): LDS 16B slot ^= (row&7) via pre-swizzled
// GLOBAL source col (gload_lds writes linearly) + same XOR on ds_read col.
// =====================================================================================
__global__ __launch_bounds__(512, 2) void gemm256(
    const unsigned short* __restrict__ A, const unsigned short* __restrict__ B,
    int K, int lda, int ldb, unsigned short* __restrict__ C, int ldc)
{
  __shared__ __align__(16) unsigned short As[32768];  // 64 KiB
  __shared__ __align__(16) unsigned short Bs[32768];  // 64 KiB

  const int tid  = threadIdx.x;
  const int lane = tid & 63;
  const int wave = tid >> 6;                 // 0..7
  const int wm   = wave >> 2, wn = wave & 3; // 2M x 4N wave grid
  const int quad = lane >> 4, l16 = lane & 15, r7 = lane & 7;
  const long tileM = (long)blockIdx.y * 256;
  const long tileN = (long)blockIdx.x * 256;

  // staging: per-lane offset (1 VGPR each); uniform (c,h,t) parts fold into SGPR base.
  // col pre-swizzled: global col-block (lane&7)^(lane>>3) -> LDS slot (lane&7)=g^(row&7)
  const unsigned scol  = (((lane & 7) ^ (lane >> 3)) * 8u);
  const unsigned aoffL = (unsigned)(tileM + wave * 8 + (lane >> 3)) * (unsigned)lda + scol;
  const unsigned boffL = (unsigned)(tileN + (wave >> 2) * 64 + (wave & 3) * 8 + (lane >> 3))
                           * (unsigned)ldb + scol;

#define ST_A(d, h, t) { \
    gload16(A + aoffL + (unsigned)((h) * 64) * (unsigned)lda + (unsigned)(t) * 64u, \
            &As[(d) * 16384 + (h) * 8192 + wave * 512]); \
    gload16(A + aoffL + (unsigned)(128 + (h) * 64) * (unsigned)lda + (unsigned)(t) * 64u, \
            &As[(d) * 16384 + (h) * 8192 + wave * 512 + 4096]); }
#define ST_B(d, h, t) { \
    gload16(B + boffL + (unsigned)((h) * 32) * (unsigned)ldb + (unsigned)(t) * 64u, \
            &Bs[(d) * 16384 + (h) * 8192 + wave * 512]); \
    gload16(B + boffL + (unsigned)(128 + (h) * 32) * (unsigned)ldb + (unsigned)(t) * 64u, \
            &Bs[(d) * 16384 + (h) * 8192 + wave * 512 + 4096]); }

  const int ax = wm * 4096 + l16 * 64;       // within A half region (elems)
  const int bx = wn * 2048 + l16 * 64;       // within B half region
  const int c0 = (quad ^ r7) * 8;            // swizzled col, K-step 0
  const int c1 = ((4 + quad) ^ r7) * 8;      // swizzled col, K-step 1

  s16x8 af0[4][2], af1[4][2], bA[2][2], bB[2][2];
  f32x4 acc[8][4] = {};

#define LD_A(d, Mh, dst) { const unsigned short* p_ = &As[(d) * 16384 + (Mh) * 8192 + ax]; \
    _Pragma("unroll") for (int ml = 0; ml < 4; ++ml) { \
      dst[ml][0] = *(const s16x8*)(p_ + ml * 1024 + c0); \
      dst[ml][1] = *(const s16x8*)(p_ + ml * 1024 + c1); } }
#define LD_B(d, Nh, dst) { const unsigned short* p_ = &Bs[(d) * 16384 + (Nh) * 8192 + bx]; \
    _Pragma("unroll") for (int nl = 0; nl < 2; ++nl) { \
      dst[nl][0] = *(const s16x8*)(p_ + nl * 1024 + c0); \
      dst[nl][1] = *(const s16x8*)(p_ + nl * 1024 + c1); } }
// ks OUTERMOST: consecutive MFMAs hit 8 distinct accumulators before any reuse
#define QMM(Mh, Nh, afv, bb) \
    _Pragma("unroll") for (int ks = 0; ks < 2; ++ks) \
    _Pragma("unroll") for (int ml = 0; ml < 4; ++ml) \
    _Pragma("unroll") for (int nl = 0; nl < 2; ++nl) \
      acc[(Mh) * 4 + ml][(Nh) * 2 + nl] = __builtin_amdgcn_mfma_f32_16x16x32_bf16( \
          afv[ml][ks], bb[nl][ks], acc[(Mh) * 4 + ml][(Nh) * 2 + nl], 0, 0, 0);
#define BAR  __builtin_amdgcn_s_barrier()
#define SCHB __builtin_amdgcn_sched_barrier(0)

  const int NT = K >> 6;   // K-tiles of 64; requires NT >= 2 (K=2048 -> 32)

  // prologue: stage tile0 fully into buf0, drain, read t=0 ph1 frags
  ST_B(0, 0, 0); ST_A(0, 0, 0); ST_B(0, 1, 0); ST_A(0, 1, 0);
  asm volatile("s_waitcnt vmcnt(0)" ::: "memory");
  BAR;
  LD_A(0, 0, af0); LD_B(0, 0, bA);

  for (int t = 0; t < NT; ++t) {
    const int cur = t & 1, nxt = cur ^ 1;
    const bool s1 = (t + 1 < NT);
    // ---- ph1: rd bB; ST B-Nh0,A-Mh0(t+1); MFMA Q00
    LD_B(cur, 1, bB);
    if (s1) { ST_B(nxt, 0, t + 1); ST_A(nxt, 0, t + 1); }
    SCHB;
    __builtin_amdgcn_s_setprio(1); QMM(0, 0, af0, bA); __builtin_amdgcn_s_setprio(0);
    if (s1) { asm volatile("s_waitcnt vmcnt(4)" ::: "memory"); }   // A-Mh1(t) landed
    else    { asm volatile("s_waitcnt vmcnt(0)" ::: "memory"); }
    BAR;
    // ---- ph2: rd af1; ST B-Nh1(t+1); MFMA Q01
    LD_A(cur, 1, af1);
    if (s1) ST_B(nxt, 1, t + 1);
    SCHB;
    __builtin_amdgcn_s_setprio(1); QMM(0, 1, af0, bB); __builtin_amdgcn_s_setprio(0);
    if (s1) { asm volatile("s_waitcnt vmcnt(2)" ::: "memory"); }   // B0/A0(t+1) landed
    BAR;
    // ---- ph3: ST A-Mh1(t+1); MFMA Q10; THEN rd bA(t+1) (WAR: MFMA uses old bA)
    if (s1) ST_A(nxt, 1, t + 1);
    SCHB;
    __builtin_amdgcn_s_setprio(1); QMM(1, 0, af1, bA); __builtin_amdgcn_s_setprio(0);
    if (s1) LD_B(nxt, 0, bA);
    BAR;
    // ---- ph4: rd af0(t+1); MFMA Q11
    if (s1) LD_A(nxt, 0, af0);
    SCHB;
    __builtin_amdgcn_s_setprio(1); QMM(1, 1, af1, bB); __builtin_amdgcn_s_setprio(0);
    if (s1) { asm volatile("s_waitcnt vmcnt(2)" ::: "memory"); }   // B-Nh1(t+1) landed
    BAR;
  }

  // epilogue: C/D layout col=l16, row=quad*4+reg (verified m89/m91)
#pragma unroll
  for (int mf = 0; mf < 8; ++mf) {
    long r0 = tileM + wm * 128 + mf * 16 + quad * 4;
#pragma unroll
    for (int nf = 0; nf < 4; ++nf) {
      long col = tileN + wn * 64 + nf * 16 + l16;
#pragma unroll
      for (int r = 0; r < 4; ++r)
        C[(r0 + r) * ldc + col] = f2bf(acc[mf][nf][r]);
    }
  }
#undef ST_A
#undef ST_B
#undef LD_A
#undef LD_B
#undef QMM
#undef BAR
#undef SCHB
}

// ---------------- bf16 MFMA GEMM, dbuf global_load_lds pipeline (one barrier/K-iter).
// Retained for small-grid shapes (encoder N=2048: 256 blocks; head N=128).
// C(MxN) = A(MxK,row) * B(NxK,row)^T.  grid x = B-tiles, y = A-tiles.
// MODE 1: bf16(tanh(acc+bias[col])) (encoder). MODE 2: f32 store (head).
template <int MODE>
__global__ __launch_bounds__(256, 4) void gemm_bt(
    const unsigned short* __restrict__ A, const unsigned short* __restrict__ B,
    int K, int lda, int ldb,
    unsigned short* __restrict__ Cb, float* __restrict__ Cf, int ldc,
    const float* __restrict__ bias)
{
  __shared__ __align__(16) unsigned short As0[2 * 128 * 32];
  __shared__ __align__(16) unsigned short Bs0[2 * 128 * 32];
  const int tid  = threadIdx.x;
  const int lane = tid & 63;
  const int wave = tid >> 6;
  const int wm = wave >> 1, wn = wave & 1;
  const int quad = lane >> 4, l16 = lane & 15;
  const long tileM = (long)blockIdx.y * 128;
  const long tileN = (long)blockIdx.x * 128;

  const int srow = lane >> 2;
  const int skc  = (lane & 3) * 8;
  const unsigned short* gA = &A[(tileM + wave * 32 + srow) * lda + skc];
  const unsigned short* gB = &B[(tileN + wave * 32 + srow) * ldb + skc];
  const int ldsOff = wave * 32 * 32;

  f32x4 acc[4][4] = {};
  const int nIt = K >> 5;

  gload16(gA, &As0[ldsOff]);
  gload16(gA + 16 * lda, &As0[ldsOff + 16 * 32]);
  gload16(gB, &Bs0[ldsOff]);
  gload16(gB + 16 * ldb, &Bs0[ldsOff + 16 * 32]);

  for (int i = 0; i < nIt; ++i) {
    __syncthreads();  // drains DMA(tile i) issued one MFMA-phase earlier
    const int cb = (i & 1) * 4096;
    if (i + 1 < nIt) {
      const int nb = ((i + 1) & 1) * 4096;
      const long ko = (long)(i + 1) * 32;
      gload16(gA + ko, &As0[nb + ldsOff]);
      gload16(gA + ko + 16 * lda, &As0[nb + ldsOff + 16 * 32]);
      gload16(gB + ko, &Bs0[nb + ldsOff]);
      gload16(gB + ko + 16 * ldb, &Bs0[nb + ldsOff + 16 * 32]);
    }
    s16x8 af[4], bfr[4];
#pragma unroll
    for (int ii = 0; ii < 4; ++ii)
      af[ii] = *(const s16x8*)&As0[cb + (wm * 64 + ii * 16 + l16) * 32 + quad * 8];
#pragma unroll
    for (int j = 0; j < 4; ++j)
      bfr[j] = *(const s16x8*)&Bs0[cb + (wn * 64 + j * 16 + l16) * 32 + quad * 8];
#pragma unroll
    for (int ii = 0; ii < 4; ++ii)
#pragma unroll
      for (int j = 0; j < 4; ++j)
        acc[ii][j] = __builtin_amdgcn_mfma_f32_16x16x32_bf16(af[ii], bfr[j], acc[ii][j], 0, 0, 0);
  }

  // C/D layout: col=lane&15, row=quad*4+reg  [verified m89/m91]
#pragma unroll
  for (int i = 0; i < 4; ++i) {
    long r0 = tileM + wm * 64 + i * 16 + quad * 4;
#pragma unroll
    for (int j = 0; j < 4; ++j) {
      long col = tileN + wn * 64 + j * 16 + l16;
      float bv = (MODE == 1) ? bias[col] : 0.f;
#pragma unroll
      for (int r = 0; r < 4; ++r) {
        float v = acc[i][j][r];
        if (MODE == 1) v = tanhf(v + bv);
        if (MODE == 2) Cf[(r0 + r) * ldc + col] = v;
        else           Cb[(r0 + r) * ldc + col] = f2bf(v);
      }
    }
  }
}

// ---------------- f32 -> bf16 convert, two equal-size arrays in one dispatch
__global__ void cvt4_dual(const float* __restrict__ inA, unsigned short* __restrict__ outA,
                          const float* __restrict__ inB, unsigned short* __restrict__ outB) {
  int i = blockIdx.x * 256 + threadIdx.x;  // over 512K chunks each
  f32x4 a = ((const f32x4*)inA)[i];
  f32x4 b = ((const f32x4*)inB)[i];
  s16x4 oa, ob;
#pragma unroll
  for (int c = 0; c < 4; ++c) { oa[c] = (short)f2bf(a[c]); ob[c] = (short)f2bf(b[c]); }
  ((s16x4*)outA)[i] = oa;
  ((s16x4*)outB)[i] = ob;
}

// ---------------- weights: Wihb = bf16(w_ih); W2b = bf16(w_hh - s*w_ih), s=1/(nA-1)
// (folds the -s*h@Wih^T comm term into the recurrent weight; exact for alive==1)
__global__ void buildw(const float* __restrict__ w_ih, const float* __restrict__ w_hh,
                       const float* __restrict__ nA,
                       unsigned short* __restrict__ Wihb, unsigned short* __restrict__ W2b) {
  int i = blockIdx.x * 256 + threadIdx.x;  // over GATES*HID/4 = 4M chunks
  float s = 1.0f / (nA[0] - 1.0f);
  size_t off = (size_t)i * 4;
  f32x4 a = *(const f32x4*)&w_ih[off];
  f32x4 b = *(const f32x4*)&w_hh[off];
  s16x4 oa, ob;
#pragma unroll
  for (int c = 0; c < 4; ++c) {
    oa[c] = (short)f2bf(a[c]);
    ob[c] = (short)f2bf(b[c] - s * a[c]);
  }
  *(s16x4*)&Wihb[off] = oa;
  *(s16x4*)&W2b[off] = ob;
}

// ---------------- head weights: Whd row 0..63 = act_w, 64 = val_w, 65..127 = 0
__global__ void build_whd(const float* __restrict__ act_w, const float* __restrict__ val_w,
                          unsigned short* __restrict__ whd) {
  int i = blockIdx.x * 256 + threadIdx.x;  // over 128*HID/4 = 64K chunks
  int r = i >> 9;
  int k = (i & 511) * 4;
  f32x4 v = {0.f, 0.f, 0.f, 0.f};
  if (r < 64)       v = *(const f32x4*)&act_w[(size_t)r * HID + k];
  else if (r == 64) v = *(const f32x4*)&val_w[k];
  s16x4 o;
  o[0] = (short)f2bf(v[0]); o[1] = (short)f2bf(v[1]);
  o[2] = (short)f2bf(v[2]); o[3] = (short)f2bf(v[3]);
  *(s16x4*)&whd[(size_t)r * HID + k] = o;
}

// ---------------- combined bias (plain order): bc[g] = b_ih[g] + b_hh[g]
__global__ void biasmix(const float* __restrict__ b_ih, const float* __restrict__ b_hh,
                        float* __restrict__ bc) {
  int i = blockIdx.x * 256 + threadIdx.x;
  if (i < GATES) bc[i] = b_ih[i] + b_hh[i];
}

// ---------------- n_alive reduction
__global__ void nalive_k(const float* __restrict__ alive, float* __restrict__ nA) {
  __shared__ float red[256];
  float s = 0.f;
  for (int i = threadIdx.x; i < N_AG; i += 256) s += alive[i];
  red[threadIdx.x] = s;
  __syncthreads();
  for (int st = 128; st > 0; st >>= 1) {
    if (threadIdx.x < st) red[threadIdx.x] += red[threadIdx.x + st];
    __syncthreads();
  }
  if (threadIdx.x == 0) nA[0] = red[0];
}

// ---------------- column sum over bf16 h: S[hid] += sum_n alive[n]*h[n][hid]
__global__ void colsum(const unsigned short* __restrict__ hb, const float* __restrict__ alive,
                       float* __restrict__ S) {
  int hid = blockIdx.x * 256 + threadIdx.x;
  int r0 = blockIdx.y * 128;
  float s = 0.f;
  for (int n = r0; n < r0 + 128; ++n) s += alive[n] * bf2f(hb[(size_t)n * HID + hid]);
  atomicAdd(&S[hid], s);
}

// ---------------- GEMV: q[g] = s * sum_k Wihb[g][k] * S[k]
__global__ __launch_bounds__(256) void gemv_q(const unsigned short* __restrict__ Wihb,
                                              const float* __restrict__ S,
                                              const float* __restrict__ nA,
                                              float* __restrict__ q) {
  __shared__ float Sl[HID];
  int tid = threadIdx.x, lane = tid & 63, wave = tid >> 6;
  for (int k = tid; k < HID; k += 256) Sl[k] = S[k];
  __syncthreads();
  int g = blockIdx.x * 4 + wave;
  const unsigned short* wr = Wihb + (size_t)g * HID;
  float acc = 0.f;
#pragma unroll
  for (int c = 0; c < 4; ++c) {
    int k = c * 512 + lane * 8;
    s16x8 w = *(const s16x8*)&wr[k];
#pragma unroll
    for (int e = 0; e < 8; ++e) acc += bf2f((unsigned short)w[e]) * Sl[k + e];
  }
  for (int off = 32; off; off >>= 1) acc += __shfl_xor(acc, off);
  if (lane == 0) q[g] = acc / (nA[0] - 1.0f);
}

// ---------------- LSTM pointwise: z = E1 (+ z2 + q if !first) + bc; gate order i,f,g,o
__global__ void lstm_k(const unsigned short* __restrict__ zb, const unsigned short* __restrict__ E1b,
                       const float* __restrict__ q, const float* __restrict__ bc,
                       float* __restrict__ cell, unsigned short* __restrict__ hb, int first) {
  int i = blockIdx.x * 256 + threadIdx.x;  // over N_AG*HID/4 = 1M
  int n = i >> 9;
  int hid = (i & 511) * 4;
  size_t base = (size_t)n * GATES;
  float zt[4][4];
#pragma unroll
  for (int t = 0; t < 4; ++t) {
    int off = t * HID + hid;
    s16x4 e1 = *(const s16x4*)&E1b[base + off];
    f32x4 bcv = *(const f32x4*)&bc[off];
#pragma unroll
    for (int c = 0; c < 4; ++c) zt[t][c] = bf2f((unsigned short)e1[c]) + bcv[c];
    if (!first) {
      s16x4 z2 = *(const s16x4*)&zb[base + off];
      f32x4 qv = *(const f32x4*)&q[off];
#pragma unroll
      for (int c = 0; c < 4; ++c) zt[t][c] += bf2f((unsigned short)z2[c]) + qv[c];
    }
  }
  f32x4 cold = {0.f, 0.f, 0.f, 0.f};
  if (!first) cold = ((const f32x4*)cell)[i];
  f32x4 cnew; s16x4 xb;
#pragma unroll
  for (int c = 0; c < 4; ++c) {
    float ig = sigm(zt[0][c]);
    float fg = sigm(zt[1][c]);
    float gg = tanhf(zt[2][c]);
    float og = sigm(zt[3][c]);
    cnew[c] = fg * cold[c] + ig * gg;
    float hv = og * tanhf(cnew[c]);
    xb[c] = (short)f2bf(hv);
  }
  ((f32x4*)cell)[i] = cnew;
  *(s16x4*)&hb[(size_t)n * HID + hid] = xb;
}

// ---------------- head epilogue: log_softmax over 64 logits + value; 1 wave/agent
__global__ __launch_bounds__(256) void head_ep(const float* __restrict__ zh,
                                               const float* __restrict__ act_b,
                                               const float* __restrict__ val_b,
                                               float* __restrict__ out) {
  int wave = threadIdx.x >> 6, lane = threadIdx.x & 63;
  int row = blockIdx.x * 4 + wave;
  const float* zr = zh + (size_t)row * 128;
  float a = zr[lane] + act_b[lane];
  float m = a;
  for (int off = 32; off; off >>= 1) m = fmaxf(m, __shfl_xor(m, off));
  float ex = expf(a - m), s = ex;
  for (int off = 32; off; off >>= 1) s += __shfl_xor(s, off);
  out[(size_t)row * ACT + lane] = a - m - logf(s);
  if (lane == 0) out[(size_t)N_AG * ACT + row] = zr[64] + val_b[0];
}

extern "C" void kernel_launch(void* const* d_in, const int* in_sizes, int n_in,
                              void* d_out, int out_size, void* d_ws, size_t ws_size,
                              hipStream_t stream) {
  const float* obs   = (const float*)d_in[0];
  const float* alive = (const float*)d_in[1];
  const float* enc_w = (const float*)d_in[2];
  const float* enc_b = (const float*)d_in[3];
  // d_in[4] g_w, d_in[5] g_b unused: gate = ceil(sigmoid(.)) == 1 identically
  const float* w_ih  = (const float*)d_in[6];
  const float* w_hh  = (const float*)d_in[7];
  const float* b_ih  = (const float*)d_in[8];
  const float* b_hh  = (const float*)d_in[9];
  const float* act_w = (const float*)d_in[10];
  const float* act_b = (const float*)d_in[11];
  const float* val_w = (const float*)d_in[12];
  const float* val_b = (const float*)d_in[13];
  float* out = (float*)d_out;

  char* p = (char*)d_ws;
  unsigned short* Wihb = (unsigned short*)p; p += (size_t)GATES * HID * 2;  // 32 MB
  unsigned short* W2b  = (unsigned short*)p; p += (size_t)GATES * HID * 2;  // 32 MB
  unsigned short* E1b  = (unsigned short*)p; p += (size_t)N_AG * GATES * 2; // 32 MB
  unsigned short* zb   = (unsigned short*)p; p += (size_t)N_AG * GATES * 2; // 32 MB
  unsigned short* obsb = (unsigned short*)p; p += (size_t)N_AG * OBSD * 2;  // 4 MB
  unsigned short* encb = (unsigned short*)p; p += (size_t)HID * OBSD * 2;   // 4 MB
  unsigned short* eb   = (unsigned short*)p; p += (size_t)N_AG * HID * 2;   // 8 MB
  unsigned short* hb   = (unsigned short*)p; p += (size_t)N_AG * HID * 2;   // 8 MB
  unsigned short* Whd  = (unsigned short*)p; p += (size_t)128 * HID * 2;    // 512 KB
  float* cell = (float*)p; p += (size_t)N_AG * HID * 4;                     // 16 MB
  float* zh   = (float*)p; p += (size_t)N_AG * 128 * 4;                     // 1 MB
  float* bc   = (float*)p; p += GATES * 4;
  float* q    = (float*)p; p += GATES * 4;
  float* S    = (float*)p; p += HID * 4;
  float* nA   = (float*)p; p += 256;

  cvt4_dual<<<(N_AG * OBSD / 4) / 256, 256, 0, stream>>>(obs, obsb, enc_w, encb);
  nalive_k<<<1, 256, 0, stream>>>(alive, nA);
  buildw<<<((size_t)GATES * HID / 4) / 256, 256, 0, stream>>>(w_ih, w_hh, nA, Wihb, W2b);
  build_whd<<<(128 * HID / 4) / 256, 256, 0, stream>>>(act_w, val_w, Whd);
  biasmix<<<GATES / 256, 256, 0, stream>>>(b_ih, b_hh, bc);

  // encoder: eb = bf16(tanh(obs @ enc_w^T + enc_b))  (128^2 kernel: 256-block grid)
  gemm_bt<1><<<dim3(HID / 128, N_AG / 128), 256, 0, stream>>>(
      obsb, encb, OBSD, OBSD, OBSD, eb, nullptr, HID, enc_b);

  // E1 = e @ Wih^T (bf16) — doubles as z of iter 0 (h==0, c==0).  256^2 read-ahead kernel.
  gemm256<<<dim3(GATES / 256, N_AG / 256), 512, 0, stream>>>(
      eb, Wihb, HID, HID, HID, E1b, GATES);
  lstm_k<<<(N_AG * HID / 4) / 256, 256, 0, stream>>>(nullptr, E1b, nullptr, bc, cell, hb, 1);

  for (int it = 1; it < 3; ++it) {
    hipMemsetAsync(S, 0, HID * 4, stream);
    colsum<<<dim3(HID / 256, 16), 256, 0, stream>>>(hb, alive, S);
    gemv_q<<<GATES / 4, 256, 0, stream>>>(Wihb, S, nA, q);
    // z2 = h @ W2^T, K=2048 (comm -s*h@Wih folded into W2)
    gemm256<<<dim3(GATES / 256, N_AG / 256), 512, 0, stream>>>(
        hb, W2b, HID, HID, HID, zb, GATES);
    lstm_k<<<(N_AG * HID / 4) / 256, 256, 0, stream>>>(zb, E1b, q, bc, cell, hb, 0);
  }

  // head: zh(2048x128) = h @ Whd^T via MFMA, then log_softmax + value epilogue
  gemm_bt<2><<<dim3(1, N_AG / 128), 256, 0, stream>>>(
      hb, Whd, HID, HID, HID, nullptr, zh, 128, nullptr);
  head_ep<<<N_AG / 4, 256, 0, stream>>>(zh, act_b, val_b, out);
}

// Round 4
// 537.178 us; speedup vs baseline: 1.0729x; 1.0519x over previous
//
#include <hip/hip_runtime.h>
#include <cmath>

#define N_AG 2048
#define HID  2048
#define OBSD 1024
#define ACT  64
#define GATES (4*HID)   // 8192

typedef short s16x8 __attribute__((ext_vector_type(8)));
typedef short s16x4 __attribute__((ext_vector_type(4)));
typedef float f32x4 __attribute__((ext_vector_type(4)));

__device__ __forceinline__ unsigned short f2bf(float f) {
  union { float f; unsigned u; } v; v.f = f;
  return (unsigned short)((v.u + 0x7FFFu + ((v.u >> 16) & 1u)) >> 16);
}
__device__ __forceinline__ float bf2f(unsigned short u) {
  union { float f; unsigned u; } v; v.u = ((unsigned)u) << 16;
  return v.f;
}
__device__ __forceinline__ float sigm(float x) { return 1.0f / (1.0f + expf(-x)); }

// async global->LDS DMA, 16B per lane; LDS dest = wave-uniform base + lane*16
__device__ __forceinline__ void gload16(const unsigned short* g, unsigned short* l) {
  __builtin_amdgcn_global_load_lds(
      (const __attribute__((address_space(1))) void*)g,
      (__attribute__((address_space(3))) void*)l, 16, 0, 0);
}

// Gate-interleaved column index: c = (hid>>4)*64 + g*16 + (hid&15).
// Inverse: g = (c>>4)&3, hid = ((c>>6)<<4) | (c&15).
// Within a wave's 64-col strip the 4 gates of one hid sit at nf=0..3, SAME l16 ->
// the LSTM pointwise is per-lane in the GEMM epilogue (no cross-lane traffic).

// =====================================================================================
// 256x256 bf16 GEMM + fused LSTM epilogue. C = A(MxK,row) * B(NxK,row)^T.
// 512 thr = 8 waves (2M x 4N), per-wave out 128x64, BK=64, LDS 128 KiB dbuf, 1 blk/CU.
// K-loop schedule = R3 (4-phase read-ahead; R1/R2/R3 all ~38% MfmaUtil — schedule
// lever exhausted at source level; this round attacks the non-GEMM pipeline instead).
// MODE 10 (E1 pass, iter 0): writes E1b = bf16(raw acc); LSTM with c_old=0, z=acc+bc;
//   writes cell(f32), hN(bf16).
// MODE 11 (z2 pass, iters 1,2): z = acc + E1b + q + bc; LSTM step; writes cell, hN.
//   A = h_prev (double-buffered vs hN written here: cross-block RAW hazard on h).
//   cell is touched by exactly one block per (agent,hid): block-exclusive, no hazard.
// =====================================================================================
template <int MODE>
__global__ __launch_bounds__(512, 2) void gemm256(
    const unsigned short* __restrict__ A, const unsigned short* __restrict__ B,
    int K, int lda, int ldb,
    unsigned short* __restrict__ E1b, const float* __restrict__ q,
    const float* __restrict__ bc, float* __restrict__ cell,
    unsigned short* __restrict__ hN)
{
  __shared__ __align__(16) unsigned short As[32768];  // 64 KiB
  __shared__ __align__(16) unsigned short Bs[32768];  // 64 KiB

  const int tid  = threadIdx.x;
  const int lane = tid & 63;
  const int wave = tid >> 6;                 // 0..7
  const int wm   = wave >> 2, wn = wave & 3; // 2M x 4N wave grid
  const int quad = lane >> 4, l16 = lane & 15, r7 = lane & 7;
  const long tileM = (long)blockIdx.y * 256;
  const long tileN = (long)blockIdx.x * 256;

  // staging; col pre-swizzled: global col-block (lane&7)^(lane>>3) -> LDS slot g^(row&7)
  const unsigned scol  = (((lane & 7) ^ (lane >> 3)) * 8u);
  const unsigned aoffL = (unsigned)(tileM + wave * 8 + (lane >> 3)) * (unsigned)lda + scol;
  const unsigned boffL = (unsigned)(tileN + (wave >> 2) * 64 + (wave & 3) * 8 + (lane >> 3))
                           * (unsigned)ldb + scol;

#define ST_A(d, h, t) { \
    gload16(A + aoffL + (unsigned)((h) * 64) * (unsigned)lda + (unsigned)(t) * 64u, \
            &As[(d) * 16384 + (h) * 8192 + wave * 512]); \
    gload16(A + aoffL + (unsigned)(128 + (h) * 64) * (unsigned)lda + (unsigned)(t) * 64u, \
            &As[(d) * 16384 + (h) * 8192 + wave * 512 + 4096]); }
#define ST_B(d, h, t) { \
    gload16(B + boffL + (unsigned)((h) * 32) * (unsigned)ldb + (unsigned)(t) * 64u, \
            &Bs[(d) * 16384 + (h) * 8192 + wave * 512]); \
    gload16(B + boffL + (unsigned)(128 + (h) * 32) * (unsigned)ldb + (unsigned)(t) * 64u, \
            &Bs[(d) * 16384 + (h) * 8192 + wave * 512 + 4096]); }

  const int ax = wm * 4096 + l16 * 64;       // within A half region (elems)
  const int bx = wn * 2048 + l16 * 64;       // within B half region
  const int c0 = (quad ^ r7) * 8;            // swizzled col, K-step 0
  const int c1 = ((4 + quad) ^ r7) * 8;      // swizzled col, K-step 1

  s16x8 af0[4][2], af1[4][2], bA[2][2], bB[2][2];
  f32x4 acc[8][4] = {};

#define LD_A(d, Mh, dst) { const unsigned short* p_ = &As[(d) * 16384 + (Mh) * 8192 + ax]; \
    _Pragma("unroll") for (int ml = 0; ml < 4; ++ml) { \
      dst[ml][0] = *(const s16x8*)(p_ + ml * 1024 + c0); \
      dst[ml][1] = *(const s16x8*)(p_ + ml * 1024 + c1); } }
#define LD_B(d, Nh, dst) { const unsigned short* p_ = &Bs[(d) * 16384 + (Nh) * 8192 + bx]; \
    _Pragma("unroll") for (int nl = 0; nl < 2; ++nl) { \
      dst[nl][0] = *(const s16x8*)(p_ + nl * 1024 + c0); \
      dst[nl][1] = *(const s16x8*)(p_ + nl * 1024 + c1); } }
#define QMM(Mh, Nh, afv, bb) \
    _Pragma("unroll") for (int ks = 0; ks < 2; ++ks) \
    _Pragma("unroll") for (int ml = 0; ml < 4; ++ml) \
    _Pragma("unroll") for (int nl = 0; nl < 2; ++nl) \
      acc[(Mh) * 4 + ml][(Nh) * 2 + nl] = __builtin_amdgcn_mfma_f32_16x16x32_bf16( \
          afv[ml][ks], bb[nl][ks], acc[(Mh) * 4 + ml][(Nh) * 2 + nl], 0, 0, 0);
#define BAR  __builtin_amdgcn_s_barrier()
#define SCHB __builtin_amdgcn_sched_barrier(0)

  const int NT = K >> 6;   // K-tiles of 64

  ST_B(0, 0, 0); ST_A(0, 0, 0); ST_B(0, 1, 0); ST_A(0, 1, 0);
  asm volatile("s_waitcnt vmcnt(0)" ::: "memory");
  BAR;
  LD_A(0, 0, af0); LD_B(0, 0, bA);

  for (int t = 0; t < NT; ++t) {
    const int cur = t & 1, nxt = cur ^ 1;
    const bool s1 = (t + 1 < NT);
    LD_B(cur, 1, bB);
    if (s1) { ST_B(nxt, 0, t + 1); ST_A(nxt, 0, t + 1); }
    SCHB;
    __builtin_amdgcn_s_setprio(1); QMM(0, 0, af0, bA); __builtin_amdgcn_s_setprio(0);
    if (s1) { asm volatile("s_waitcnt vmcnt(4)" ::: "memory"); }
    else    { asm volatile("s_waitcnt vmcnt(0)" ::: "memory"); }
    BAR;
    LD_A(cur, 1, af1);
    if (s1) ST_B(nxt, 1, t + 1);
    SCHB;
    __builtin_amdgcn_s_setprio(1); QMM(0, 1, af0, bB); __builtin_amdgcn_s_setprio(0);
    if (s1) { asm volatile("s_waitcnt vmcnt(2)" ::: "memory"); }
    BAR;
    if (s1) ST_A(nxt, 1, t + 1);
    SCHB;
    __builtin_amdgcn_s_setprio(1); QMM(1, 0, af1, bA); __builtin_amdgcn_s_setprio(0);
    if (s1) LD_B(nxt, 0, bA);
    BAR;
    if (s1) LD_A(nxt, 0, af0);
    SCHB;
    __builtin_amdgcn_s_setprio(1); QMM(1, 1, af1, bB); __builtin_amdgcn_s_setprio(0);
    if (s1) { asm volatile("s_waitcnt vmcnt(2)" ::: "memory"); }
    BAR;
  }

  // ---- fused LSTM epilogue. C/D layout: col=l16, row=quad*4+reg [m89/m91].
  // col = tileN + wn*64 + nf*16 + l16; with interleaved layout nf == gate g and
  // hid = ((tileN+wn*64)>>6)*16 + l16 is lane-constant.
  const int cb0 = (int)tileN + wn * 64;
  const int hid = ((cb0 >> 6) << 4) | l16;
  float bcv[4], qv[4];
#pragma unroll
  for (int g = 0; g < 4; ++g) {
    bcv[g] = bc[cb0 + g * 16 + l16];
    qv[g]  = (MODE == 11) ? q[cb0 + g * 16 + l16] : 0.f;
  }
#pragma unroll
  for (int mf = 0; mf < 8; ++mf) {
    long ag0 = tileM + wm * 128 + mf * 16 + quad * 4;
#pragma unroll
    for (int r = 0; r < 4; ++r) {
      long ag = ag0 + r;
      size_t eb_i = (size_t)ag * GATES + cb0 + l16;
      float zi = acc[mf][0][r], zf = acc[mf][1][r];
      float zg = acc[mf][2][r], zo = acc[mf][3][r];
      if (MODE == 10) {
        E1b[eb_i]      = f2bf(zi);
        E1b[eb_i + 16] = f2bf(zf);
        E1b[eb_i + 32] = f2bf(zg);
        E1b[eb_i + 48] = f2bf(zo);
        zi += bcv[0]; zf += bcv[1]; zg += bcv[2]; zo += bcv[3];
      } else {
        zi += bf2f(E1b[eb_i])      + qv[0] + bcv[0];
        zf += bf2f(E1b[eb_i + 16]) + qv[1] + bcv[1];
        zg += bf2f(E1b[eb_i + 32]) + qv[2] + bcv[2];
        zo += bf2f(E1b[eb_i + 48]) + qv[3] + bcv[3];
      }
      float cold = (MODE == 10) ? 0.f : cell[(size_t)ag * HID + hid];
      float cnew = sigm(zf) * cold + sigm(zi) * tanhf(zg);
      float hv   = sigm(zo) * tanhf(cnew);
      cell[(size_t)ag * HID + hid] = cnew;
      hN[(size_t)ag * HID + hid]   = f2bf(hv);
    }
  }
#undef ST_A
#undef ST_B
#undef LD_A
#undef LD_B
#undef QMM
#undef BAR
#undef SCHB
}

// ---------------- bf16 MFMA GEMM, dbuf global_load_lds pipeline (one barrier/K-iter).
// Small-grid shapes. C(MxN) = A(MxK,row) * B(NxK,row)^T. grid x = B-tiles, y = A-tiles,
// z = K-split (koff = blockIdx.z*K). MODE 1: bf16(tanh(acc+bias[col])) (encoder).
// MODE 2: f32 atomicAdd into Cf (head split-K; Cf pre-zeroed).
template <int MODE>
__global__ __launch_bounds__(256, 4) void gemm_bt(
    const unsigned short* __restrict__ A, const unsigned short* __restrict__ B,
    int K, int lda, int ldb,
    unsigned short* __restrict__ Cb, float* __restrict__ Cf, int ldc,
    const float* __restrict__ bias)
{
  __shared__ __align__(16) unsigned short As0[2 * 128 * 32];
  __shared__ __align__(16) unsigned short Bs0[2 * 128 * 32];
  const int tid  = threadIdx.x;
  const int lane = tid & 63;
  const int wave = tid >> 6;
  const int wm = wave >> 1, wn = wave & 1;
  const int quad = lane >> 4, l16 = lane & 15;
  const long tileM = (long)blockIdx.y * 128;
  const long tileN = (long)blockIdx.x * 128;
  const long koff  = (long)blockIdx.z * K;

  const int srow = lane >> 2;
  const int skc  = (lane & 3) * 8;
  const unsigned short* gA = &A[(tileM + wave * 32 + srow) * lda + koff + skc];
  const unsigned short* gB = &B[(tileN + wave * 32 + srow) * ldb + koff + skc];
  const int ldsOff = wave * 32 * 32;

  f32x4 acc[4][4] = {};
  const int nIt = K >> 5;

  gload16(gA, &As0[ldsOff]);
  gload16(gA + 16 * lda, &As0[ldsOff + 16 * 32]);
  gload16(gB, &Bs0[ldsOff]);
  gload16(gB + 16 * ldb, &Bs0[ldsOff + 16 * 32]);

  for (int i = 0; i < nIt; ++i) {
    __syncthreads();
    const int cb = (i & 1) * 4096;
    if (i + 1 < nIt) {
      const int nb = ((i + 1) & 1) * 4096;
      const long ko = (long)(i + 1) * 32;
      gload16(gA + ko, &As0[nb + ldsOff]);
      gload16(gA + ko + 16 * lda, &As0[nb + ldsOff + 16 * 32]);
      gload16(gB + ko, &Bs0[nb + ldsOff]);
      gload16(gB + ko + 16 * ldb, &Bs0[nb + ldsOff + 16 * 32]);
    }
    s16x8 af[4], bfr[4];
#pragma unroll
    for (int ii = 0; ii < 4; ++ii)
      af[ii] = *(const s16x8*)&As0[cb + (wm * 64 + ii * 16 + l16) * 32 + quad * 8];
#pragma unroll
    for (int j = 0; j < 4; ++j)
      bfr[j] = *(const s16x8*)&Bs0[cb + (wn * 64 + j * 16 + l16) * 32 + quad * 8];
#pragma unroll
    for (int ii = 0; ii < 4; ++ii)
#pragma unroll
      for (int j = 0; j < 4; ++j)
        acc[ii][j] = __builtin_amdgcn_mfma_f32_16x16x32_bf16(af[ii], bfr[j], acc[ii][j], 0, 0, 0);
  }

#pragma unroll
  for (int i = 0; i < 4; ++i) {
    long r0 = tileM + wm * 64 + i * 16 + quad * 4;
#pragma unroll
    for (int j = 0; j < 4; ++j) {
      long col = tileN + wn * 64 + j * 16 + l16;
      float bv = (MODE == 1) ? bias[col] : 0.f;
#pragma unroll
      for (int r = 0; r < 4; ++r) {
        float v = acc[i][j][r];
        if (MODE == 1) { v = tanhf(v + bv); Cb[(r0 + r) * ldc + col] = f2bf(v); }
        if (MODE == 2) atomicAdd(&Cf[(r0 + r) * ldc + col], v);
      }
    }
  }
}

// ---------------- f32 -> bf16 convert, two equal-size arrays in one dispatch
__global__ void cvt4_dual(const float* __restrict__ inA, unsigned short* __restrict__ outA,
                          const float* __restrict__ inB, unsigned short* __restrict__ outB) {
  int i = blockIdx.x * 256 + threadIdx.x;
  f32x4 a = ((const f32x4*)inA)[i];
  f32x4 b = ((const f32x4*)inB)[i];
  s16x4 oa, ob;
#pragma unroll
  for (int c = 0; c < 4; ++c) { oa[c] = (short)f2bf(a[c]); ob[c] = (short)f2bf(b[c]); }
  ((s16x4*)outA)[i] = oa;
  ((s16x4*)outB)[i] = ob;
}

// ---------------- weights, GATE-INTERLEAVED rows: output row c <- source row
// sr(c) = g*HID + hid, g=(c>>4)&3, hid=((c>>6)<<4)|(c&15).
// Wihb = bf16(w_ih); W2b = bf16(w_hh - s*w_ih), s=1/(nA-1) (comm fold, alive==1).
__global__ void buildw(const float* __restrict__ w_ih, const float* __restrict__ w_hh,
                       const float* __restrict__ nA,
                       unsigned short* __restrict__ Wihb, unsigned short* __restrict__ W2b) {
  int i = blockIdx.x * 256 + threadIdx.x;  // over GATES*HID/4 = 4M chunks
  float s = 1.0f / (nA[0] - 1.0f);
  int c  = i >> 9;
  int kk = (i & 511) * 4;
  int g   = (c >> 4) & 3;
  int hid = ((c >> 6) << 4) | (c & 15);
  size_t src = ((size_t)g * HID + hid) * HID + kk;
  size_t dst = (size_t)c * HID + kk;
  f32x4 a = *(const f32x4*)&w_ih[src];
  f32x4 b = *(const f32x4*)&w_hh[src];
  s16x4 oa, ob;
#pragma unroll
  for (int e = 0; e < 4; ++e) {
    oa[e] = (short)f2bf(a[e]);
    ob[e] = (short)f2bf(b[e] - s * a[e]);
  }
  *(s16x4*)&Wihb[dst] = oa;
  *(s16x4*)&W2b[dst] = ob;
}

// ---------------- head weights: Whd row 0..63 = act_w, 64 = val_w, 65..127 = 0
__global__ void build_whd(const float* __restrict__ act_w, const float* __restrict__ val_w,
                          unsigned short* __restrict__ whd) {
  int i = blockIdx.x * 256 + threadIdx.x;
  int r = i >> 9;
  int k = (i & 511) * 4;
  f32x4 v = {0.f, 0.f, 0.f, 0.f};
  if (r < 64)       v = *(const f32x4*)&act_w[(size_t)r * HID + k];
  else if (r == 64) v = *(const f32x4*)&val_w[k];
  s16x4 o;
  o[0] = (short)f2bf(v[0]); o[1] = (short)f2bf(v[1]);
  o[2] = (short)f2bf(v[2]); o[3] = (short)f2bf(v[3]);
  *(s16x4*)&whd[(size_t)r * HID + k] = o;
}

// ---------------- combined bias, interleaved: bc[c] = b_ih[sr(c)] + b_hh[sr(c)]
__global__ void biasmix(const float* __restrict__ b_ih, const float* __restrict__ b_hh,
                        float* __restrict__ bc) {
  int i = blockIdx.x * 256 + threadIdx.x;
  if (i < GATES) {
    int g   = (i >> 4) & 3;
    int hid = ((i >> 6) << 4) | (i & 15);
    int src = g * HID + hid;
    bc[i] = b_ih[src] + b_hh[src];
  }
}

// ---------------- n_alive reduction
__global__ void nalive_k(const float* __restrict__ alive, float* __restrict__ nA) {
  __shared__ float red[256];
  float s = 0.f;
  for (int i = threadIdx.x; i < N_AG; i += 256) s += alive[i];
  red[threadIdx.x] = s;
  __syncthreads();
  for (int st = 128; st > 0; st >>= 1) {
    if (threadIdx.x < st) red[threadIdx.x] += red[threadIdx.x + st];
    __syncthreads();
  }
  if (threadIdx.x == 0) nA[0] = red[0];
}

// ---------------- column sum over bf16 h: S[hid] += sum_n alive[n]*h[n][hid]
__global__ void colsum(const unsigned short* __restrict__ hb, const float* __restrict__ alive,
                       float* __restrict__ S) {
  int hid = blockIdx.x * 256 + threadIdx.x;
  int r0 = blockIdx.y * 128;
  float s = 0.f;
  for (int n = r0; n < r0 + 128; ++n) s += alive[n] * bf2f(hb[(size_t)n * HID + hid]);
  atomicAdd(&S[hid], s);
}

// ---------------- GEMV: q[c] = sum_k Wihb[c][k]*S[k] / (nA-1)  (rows interleaved ->
// q comes out interleaved, matching the fused epilogue's col index)
__global__ __launch_bounds__(256) void gemv_q(const unsigned short* __restrict__ Wihb,
                                              const float* __restrict__ S,
                                              const float* __restrict__ nA,
                                              float* __restrict__ q) {
  __shared__ float Sl[HID];
  int tid = threadIdx.x, lane = tid & 63, wave = tid >> 6;
  for (int k = tid; k < HID; k += 256) Sl[k] = S[k];
  __syncthreads();
  int g = blockIdx.x * 4 + wave;
  const unsigned short* wr = Wihb + (size_t)g * HID;
  float acc = 0.f;
#pragma unroll
  for (int c = 0; c < 4; ++c) {
    int k = c * 512 + lane * 8;
    s16x8 w = *(const s16x8*)&wr[k];
#pragma unroll
    for (int e = 0; e < 8; ++e) acc += bf2f((unsigned short)w[e]) * Sl[k + e];
  }
  for (int off = 32; off; off >>= 1) acc += __shfl_xor(acc, off);
  if (lane == 0) q[g] = acc / (nA[0] - 1.0f);
}

// ---------------- head epilogue: log_softmax over 64 logits + value; 1 wave/agent
__global__ __launch_bounds__(256) void head_ep(const float* __restrict__ zh,
                                               const float* __restrict__ act_b,
                                               const float* __restrict__ val_b,
                                               float* __restrict__ out) {
  int wave = threadIdx.x >> 6, lane = threadIdx.x & 63;
  int row = blockIdx.x * 4 + wave;
  const float* zr = zh + (size_t)row * 128;
  float a = zr[lane] + act_b[lane];
  float m = a;
  for (int off = 32; off; off >>= 1) m = fmaxf(m, __shfl_xor(m, off));
  float ex = expf(a - m), s = ex;
  for (int off = 32; off; off >>= 1) s += __shfl_xor(s, off);
  out[(size_t)row * ACT + lane] = a - m - logf(s);
  if (lane == 0) out[(size_t)N_AG * ACT + row] = zr[64] + val_b[0];
}

extern "C" void kernel_launch(void* const* d_in, const int* in_sizes, int n_in,
                              void* d_out, int out_size, void* d_ws, size_t ws_size,
                              hipStream_t stream) {
  const float* obs   = (const float*)d_in[0];
  const float* alive = (const float*)d_in[1];
  const float* enc_w = (const float*)d_in[2];
  const float* enc_b = (const float*)d_in[3];
  // d_in[4] g_w, d_in[5] g_b unused: gate = ceil(sigmoid(.)) == 1 identically
  const float* w_ih  = (const float*)d_in[6];
  const float* w_hh  = (const float*)d_in[7];
  const float* b_ih  = (const float*)d_in[8];
  const float* b_hh  = (const float*)d_in[9];
  const float* act_w = (const float*)d_in[10];
  const float* act_b = (const float*)d_in[11];
  const float* val_w = (const float*)d_in[12];
  const float* val_b = (const float*)d_in[13];
  float* out = (float*)d_out;

  char* p = (char*)d_ws;
  unsigned short* Wihb = (unsigned short*)p; p += (size_t)GATES * HID * 2;  // 32 MB
  unsigned short* W2b  = (unsigned short*)p; p += (size_t)GATES * HID * 2;  // 32 MB
  unsigned short* E1b  = (unsigned short*)p; p += (size_t)N_AG * GATES * 2; // 32 MB
  unsigned short* obsb = (unsigned short*)p; p += (size_t)N_AG * OBSD * 2;  // 4 MB
  unsigned short* encb = (unsigned short*)p; p += (size_t)HID * OBSD * 2;   // 4 MB
  unsigned short* eb   = (unsigned short*)p; p += (size_t)N_AG * HID * 2;   // 8 MB
  unsigned short* h0   = (unsigned short*)p; p += (size_t)N_AG * HID * 2;   // 8 MB
  unsigned short* h1   = (unsigned short*)p; p += (size_t)N_AG * HID * 2;   // 8 MB
  unsigned short* Whd  = (unsigned short*)p; p += (size_t)128 * HID * 2;    // 512 KB
  float* cell = (float*)p; p += (size_t)N_AG * HID * 4;                     // 16 MB
  float* zh   = (float*)p; p += (size_t)N_AG * 128 * 4;                     // 1 MB
  float* bc   = (float*)p; p += GATES * 4;
  float* q    = (float*)p; p += GATES * 4;
  float* S    = (float*)p; p += HID * 4;
  float* nA   = (float*)p; p += 256;

  cvt4_dual<<<(N_AG * OBSD / 4) / 256, 256, 0, stream>>>(obs, obsb, enc_w, encb);
  nalive_k<<<1, 256, 0, stream>>>(alive, nA);
  buildw<<<((size_t)GATES * HID / 4) / 256, 256, 0, stream>>>(w_ih, w_hh, nA, Wihb, W2b);
  build_whd<<<(128 * HID / 4) / 256, 256, 0, stream>>>(act_w, val_w, Whd);
  biasmix<<<GATES / 256, 256, 0, stream>>>(b_ih, b_hh, bc);

  // encoder: eb = bf16(tanh(obs @ enc_w^T + enc_b))
  gemm_bt<1><<<dim3(HID / 128, N_AG / 128), 256, 0, stream>>>(
      obsb, encb, OBSD, OBSD, OBSD, eb, nullptr, HID, enc_b);

  // iter 0 fused: E1 = e @ Wih^T (store bf16) + LSTM(c=0) -> cell, h0
  gemm256<10><<<dim3(GATES / 256, N_AG / 256), 512, 0, stream>>>(
      eb, Wihb, HID, HID, HID, E1b, nullptr, bc, cell, h0);

  unsigned short* hcur = h0;
  unsigned short* hnxt = h1;
  for (int it = 1; it < 3; ++it) {
    hipMemsetAsync(S, 0, HID * 4, stream);
    colsum<<<dim3(HID / 256, 16), 256, 0, stream>>>(hcur, alive, S);
    gemv_q<<<GATES / 4, 256, 0, stream>>>(Wihb, S, nA, q);
    // fused: z2 = h @ W2^T (f32 acc) + E1 + q + bc -> LSTM step -> cell, hnxt
    gemm256<11><<<dim3(GATES / 256, N_AG / 256), 512, 0, stream>>>(
        hcur, W2b, HID, HID, HID, E1b, q, bc, cell, hnxt);
    unsigned short* tmp = hcur; hcur = hnxt; hnxt = tmp;
  }

  // head: zh(2048x128) = h @ Whd^T, split-K x8 via f32 atomics (128 blocks vs 16)
  hipMemsetAsync(zh, 0, (size_t)N_AG * 128 * 4, stream);
  gemm_bt<2><<<dim3(1, N_AG / 128, 8), 256, 0, stream>>>(
      hcur, Whd, HID / 8, HID, HID, nullptr, zh, 128, nullptr);
  head_ep<<<N_AG / 4, 256, 0, stream>>>(zh, act_b, val_b, out);
}

// Round 5
// 477.639 us; speedup vs baseline: 1.2067x; 1.1247x over previous
//
#include <hip/hip_runtime.h>
#include <cmath>

#define N_AG 2048
#define HID  2048
#define OBSD 1024
#define ACT  64
#define GATES (4*HID)   // 8192

typedef short s16x8 __attribute__((ext_vector_type(8)));
typedef short s16x4 __attribute__((ext_vector_type(4)));
typedef float f32x4 __attribute__((ext_vector_type(4)));

__device__ __forceinline__ unsigned short f2bf(float f) {
  union { float f; unsigned u; } v; v.f = f;
  return (unsigned short)((v.u + 0x7FFFu + ((v.u >> 16) & 1u)) >> 16);
}
__device__ __forceinline__ float bf2f(unsigned short u) {
  union { float f; unsigned u; } v; v.u = ((unsigned)u) << 16;
  return v.f;
}
// Fast transcendentals (R5): native v_exp_f32 + v_rcp_f32. Overflow-safe at all x:
// exp(-x)->inf => rcp(inf)=0 => correct saturation; no clamps needed.
__device__ __forceinline__ float fsigm(float x) {
  return __builtin_amdgcn_rcpf(1.0f + __expf(-x));
}
__device__ __forceinline__ float ftanh(float x) {
  return 2.0f * __builtin_amdgcn_rcpf(1.0f + __expf(-2.0f * x)) - 1.0f;
}

// async global->LDS DMA, 16B per lane; LDS dest = wave-uniform base + lane*16
__device__ __forceinline__ void gload16(const unsigned short* g, unsigned short* l) {
  __builtin_amdgcn_global_load_lds(
      (const __attribute__((address_space(1))) void*)g,
      (__attribute__((address_space(3))) void*)l, 16, 0, 0);
}

// Gate-interleaved column index: c = (hid>>4)*64 + g*16 + (hid&15).
// Inverse: g = (c>>4)&3, hid = ((c>>6)<<4) | (c&15).
// Within a wave's 64-col strip the 4 gates of one hid sit at nf=0..3, SAME l16 ->
// the LSTM pointwise is per-lane in the GEMM epilogue (no cross-lane traffic).

// =====================================================================================
// 256x256 bf16 GEMM + fused LSTM epilogue + fused comm column-sum.
// C = A(MxK,row) * B(NxK,row)^T. 512 thr = 8 waves (2M x 4N), per-wave out 128x64,
// BK=64, LDS 128 KiB dbuf, 1 blk/CU. K-loop schedule = R3 (lever exhausted at ~38%).
// MODE 10 (iter 0): store E1 (packed); LSTM c_old=0, z=acc+bc; write cell, hN.
// MODE 11 (iters 1,2): z = acc + E1 + q + bc; LSTM step; write cell, hN.
// ACCS: accumulate S[hid] += alive[ag]*h_new[ag][hid] (quad-reduced, 1 atomic/4 lanes)
//   -> replaces the separate colsum kernel (h for the NEXT comm iteration).
// E1b & cell are PRIVATE scratch between MODE10/11 epilogues (identical grid/thread
// mapping) -> stored in packed layout [bid][slot=mf*4+r][tid]: s16x4/f32 per thread,
// perfectly coalesced, 4x fewer VMEM insts than the scattered row-major form (R4).
// =====================================================================================
template <int MODE, int ACCS>
__global__ __launch_bounds__(512, 2) void gemm256(
    const unsigned short* __restrict__ A, const unsigned short* __restrict__ B,
    int K, int lda, int ldb,
    unsigned short* __restrict__ E1b, const float* __restrict__ q,
    const float* __restrict__ bc, float* __restrict__ cell,
    unsigned short* __restrict__ hN,
    const float* __restrict__ alive, float* __restrict__ S)
{
  __shared__ __align__(16) unsigned short As[32768];  // 64 KiB
  __shared__ __align__(16) unsigned short Bs[32768];  // 64 KiB

  const int tid  = threadIdx.x;
  const int lane = tid & 63;
  const int wave = tid >> 6;                 // 0..7
  const int wm   = wave >> 2, wn = wave & 3; // 2M x 4N wave grid
  const int quad = lane >> 4, l16 = lane & 15, r7 = lane & 7;
  const long tileM = (long)blockIdx.y * 256;
  const long tileN = (long)blockIdx.x * 256;

  // staging; col pre-swizzled: global col-block (lane&7)^(lane>>3) -> LDS slot g^(row&7)
  const unsigned scol  = (((lane & 7) ^ (lane >> 3)) * 8u);
  const unsigned aoffL = (unsigned)(tileM + wave * 8 + (lane >> 3)) * (unsigned)lda + scol;
  const unsigned boffL = (unsigned)(tileN + (wave >> 2) * 64 + (wave & 3) * 8 + (lane >> 3))
                           * (unsigned)ldb + scol;

#define ST_A(d, h, t) { \
    gload16(A + aoffL + (unsigned)((h) * 64) * (unsigned)lda + (unsigned)(t) * 64u, \
            &As[(d) * 16384 + (h) * 8192 + wave * 512]); \
    gload16(A + aoffL + (unsigned)(128 + (h) * 64) * (unsigned)lda + (unsigned)(t) * 64u, \
            &As[(d) * 16384 + (h) * 8192 + wave * 512 + 4096]); }
#define ST_B(d, h, t) { \
    gload16(B + boffL + (unsigned)((h) * 32) * (unsigned)ldb + (unsigned)(t) * 64u, \
            &Bs[(d) * 16384 + (h) * 8192 + wave * 512]); \
    gload16(B + boffL + (unsigned)(128 + (h) * 32) * (unsigned)ldb + (unsigned)(t) * 64u, \
            &Bs[(d) * 16384 + (h) * 8192 + wave * 512 + 4096]); }

  const int ax = wm * 4096 + l16 * 64;       // within A half region (elems)
  const int bx = wn * 2048 + l16 * 64;       // within B half region
  const int c0 = (quad ^ r7) * 8;            // swizzled col, K-step 0
  const int c1 = ((4 + quad) ^ r7) * 8;      // swizzled col, K-step 1

  s16x8 af0[4][2], af1[4][2], bA[2][2], bB[2][2];
  f32x4 acc[8][4] = {};

#define LD_A(d, Mh, dst) { const unsigned short* p_ = &As[(d) * 16384 + (Mh) * 8192 + ax]; \
    _Pragma("unroll") for (int ml = 0; ml < 4; ++ml) { \
      dst[ml][0] = *(const s16x8*)(p_ + ml * 1024 + c0); \
      dst[ml][1] = *(const s16x8*)(p_ + ml * 1024 + c1); } }
#define LD_B(d, Nh, dst) { const unsigned short* p_ = &Bs[(d) * 16384 + (Nh) * 8192 + bx]; \
    _Pragma("unroll") for (int nl = 0; nl < 2; ++nl) { \
      dst[nl][0] = *(const s16x8*)(p_ + nl * 1024 + c0); \
      dst[nl][1] = *(const s16x8*)(p_ + nl * 1024 + c1); } }
#define QMM(Mh, Nh, afv, bb) \
    _Pragma("unroll") for (int ks = 0; ks < 2; ++ks) \
    _Pragma("unroll") for (int ml = 0; ml < 4; ++ml) \
    _Pragma("unroll") for (int nl = 0; nl < 2; ++nl) \
      acc[(Mh) * 4 + ml][(Nh) * 2 + nl] = __builtin_amdgcn_mfma_f32_16x16x32_bf16( \
          afv[ml][ks], bb[nl][ks], acc[(Mh) * 4 + ml][(Nh) * 2 + nl], 0, 0, 0);
#define BAR  __builtin_amdgcn_s_barrier()
#define SCHB __builtin_amdgcn_sched_barrier(0)

  const int NT = K >> 6;   // K-tiles of 64

  ST_B(0, 0, 0); ST_A(0, 0, 0); ST_B(0, 1, 0); ST_A(0, 1, 0);
  asm volatile("s_waitcnt vmcnt(0)" ::: "memory");
  BAR;
  LD_A(0, 0, af0); LD_B(0, 0, bA);

  for (int t = 0; t < NT; ++t) {
    const int cur = t & 1, nxt = cur ^ 1;
    const bool s1 = (t + 1 < NT);
    LD_B(cur, 1, bB);
    if (s1) { ST_B(nxt, 0, t + 1); ST_A(nxt, 0, t + 1); }
    SCHB;
    __builtin_amdgcn_s_setprio(1); QMM(0, 0, af0, bA); __builtin_amdgcn_s_setprio(0);
    if (s1) { asm volatile("s_waitcnt vmcnt(4)" ::: "memory"); }
    else    { asm volatile("s_waitcnt vmcnt(0)" ::: "memory"); }
    BAR;
    LD_A(cur, 1, af1);
    if (s1) ST_B(nxt, 1, t + 1);
    SCHB;
    __builtin_amdgcn_s_setprio(1); QMM(0, 1, af0, bB); __builtin_amdgcn_s_setprio(0);
    if (s1) { asm volatile("s_waitcnt vmcnt(2)" ::: "memory"); }
    BAR;
    if (s1) ST_A(nxt, 1, t + 1);
    SCHB;
    __builtin_amdgcn_s_setprio(1); QMM(1, 0, af1, bA); __builtin_amdgcn_s_setprio(0);
    if (s1) LD_B(nxt, 0, bA);
    BAR;
    if (s1) LD_A(nxt, 0, af0);
    SCHB;
    __builtin_amdgcn_s_setprio(1); QMM(1, 1, af1, bB); __builtin_amdgcn_s_setprio(0);
    if (s1) { asm volatile("s_waitcnt vmcnt(2)" ::: "memory"); }
    BAR;
  }

  // ---- fused LSTM epilogue. C/D layout: col=l16, row=quad*4+reg [m89/m91].
  // col = tileN + wn*64 + nf*16 + l16; interleaved layout => nf == gate g and
  // hid = ((tileN+wn*64)>>4 grouping) is lane-constant.
  const int cb0 = (int)tileN + wn * 64;
  const int hid = ((cb0 >> 6) << 4) | l16;
  const int bid = (int)blockIdx.y * (int)gridDim.x + (int)blockIdx.x;
  float bcv[4], qv[4];
#pragma unroll
  for (int g = 0; g < 4; ++g) {
    bcv[g] = bc[cb0 + g * 16 + l16];
    qv[g]  = (MODE == 11) ? q[cb0 + g * 16 + l16] : 0.f;
  }
  float sacc = 0.f;
#pragma unroll
  for (int mf = 0; mf < 8; ++mf) {
    long ag0 = tileM + wm * 128 + mf * 16 + quad * 4;
#pragma unroll
    for (int r = 0; r < 4; ++r) {
      long ag = ag0 + r;
      const size_t pk = ((size_t)bid * 32 + (mf * 4 + r)) * 512 + tid;  // packed slot
      float zi = acc[mf][0][r], zf = acc[mf][1][r];
      float zg = acc[mf][2][r], zo = acc[mf][3][r];
      if (MODE == 10) {
        s16x4 ev;
        ev[0] = (short)f2bf(zi); ev[1] = (short)f2bf(zf);
        ev[2] = (short)f2bf(zg); ev[3] = (short)f2bf(zo);
        *(s16x4*)&E1b[pk * 4] = ev;
        zi += bcv[0]; zf += bcv[1]; zg += bcv[2]; zo += bcv[3];
      } else {
        s16x4 ev = *(const s16x4*)&E1b[pk * 4];
        zi += bf2f((unsigned short)ev[0]) + qv[0] + bcv[0];
        zf += bf2f((unsigned short)ev[1]) + qv[1] + bcv[1];
        zg += bf2f((unsigned short)ev[2]) + qv[2] + bcv[2];
        zo += bf2f((unsigned short)ev[3]) + qv[3] + bcv[3];
      }
      float cold = (MODE == 10) ? 0.f : cell[pk];
      float cnew = fsigm(zf) * cold + fsigm(zi) * ftanh(zg);
      float hv   = fsigm(zo) * ftanh(cnew);
      cell[pk] = cnew;
      hN[(size_t)ag * HID + hid] = f2bf(hv);
      if (ACCS) sacc += alive[ag] * hv;
    }
  }
  if (ACCS) {
    // reduce over quad partners (lane bits 4,5 carry quad; same l16 => same hid)
    sacc += __shfl_xor(sacc, 16);
    sacc += __shfl_xor(sacc, 32);
    if (quad == 0) atomicAdd(&S[hid], sacc);
  }
#undef ST_A
#undef ST_B
#undef LD_A
#undef LD_B
#undef QMM
#undef BAR
#undef SCHB
}

// ---------------- bf16 MFMA GEMM, dbuf global_load_lds pipeline (one barrier/K-iter).
// Small-grid shapes. C(MxN) = A(MxK,row) * B(NxK,row)^T. grid x = B-tiles, y = A-tiles,
// z = K-split (koff = blockIdx.z*K). MODE 1: bf16(tanh(acc+bias[col])) (encoder).
// MODE 2: f32 atomicAdd into Cf (head split-K; Cf pre-zeroed).
template <int MODE>
__global__ __launch_bounds__(256, 4) void gemm_bt(
    const unsigned short* __restrict__ A, const unsigned short* __restrict__ B,
    int K, int lda, int ldb,
    unsigned short* __restrict__ Cb, float* __restrict__ Cf, int ldc,
    const float* __restrict__ bias)
{
  __shared__ __align__(16) unsigned short As0[2 * 128 * 32];
  __shared__ __align__(16) unsigned short Bs0[2 * 128 * 32];
  const int tid  = threadIdx.x;
  const int lane = tid & 63;
  const int wave = tid >> 6;
  const int wm = wave >> 1, wn = wave & 1;
  const int quad = lane >> 4, l16 = lane & 15;
  const long tileM = (long)blockIdx.y * 128;
  const long tileN = (long)blockIdx.x * 128;
  const long koff  = (long)blockIdx.z * K;

  const int srow = lane >> 2;
  const int skc  = (lane & 3) * 8;
  const unsigned short* gA = &A[(tileM + wave * 32 + srow) * lda + koff + skc];
  const unsigned short* gB = &B[(tileN + wave * 32 + srow) * ldb + koff + skc];
  const int ldsOff = wave * 32 * 32;

  f32x4 acc[4][4] = {};
  const int nIt = K >> 5;

  gload16(gA, &As0[ldsOff]);
  gload16(gA + 16 * lda, &As0[ldsOff + 16 * 32]);
  gload16(gB, &Bs0[ldsOff]);
  gload16(gB + 16 * ldb, &Bs0[ldsOff + 16 * 32]);

  for (int i = 0; i < nIt; ++i) {
    __syncthreads();
    const int cb = (i & 1) * 4096;
    if (i + 1 < nIt) {
      const int nb = ((i + 1) & 1) * 4096;
      const long ko = (long)(i + 1) * 32;
      gload16(gA + ko, &As0[nb + ldsOff]);
      gload16(gA + ko + 16 * lda, &As0[nb + ldsOff + 16 * 32]);
      gload16(gB + ko, &Bs0[nb + ldsOff]);
      gload16(gB + ko + 16 * ldb, &Bs0[nb + ldsOff + 16 * 32]);
    }
    s16x8 af[4], bfr[4];
#pragma unroll
    for (int ii = 0; ii < 4; ++ii)
      af[ii] = *(const s16x8*)&As0[cb + (wm * 64 + ii * 16 + l16) * 32 + quad * 8];
#pragma unroll
    for (int j = 0; j < 4; ++j)
      bfr[j] = *(const s16x8*)&Bs0[cb + (wn * 64 + j * 16 + l16) * 32 + quad * 8];
#pragma unroll
    for (int ii = 0; ii < 4; ++ii)
#pragma unroll
      for (int j = 0; j < 4; ++j)
        acc[ii][j] = __builtin_amdgcn_mfma_f32_16x16x32_bf16(af[ii], bfr[j], acc[ii][j], 0, 0, 0);
  }

#pragma unroll
  for (int i = 0; i < 4; ++i) {
    long r0 = tileM + wm * 64 + i * 16 + quad * 4;
#pragma unroll
    for (int j = 0; j < 4; ++j) {
      long col = tileN + wn * 64 + j * 16 + l16;
      float bv = (MODE == 1) ? bias[col] : 0.f;
#pragma unroll
      for (int r = 0; r < 4; ++r) {
        float v = acc[i][j][r];
        if (MODE == 1) { v = ftanh(v + bv); Cb[(r0 + r) * ldc + col] = f2bf(v); }
        if (MODE == 2) atomicAdd(&Cf[(r0 + r) * ldc + col], v);
      }
    }
  }
}

// ---------------- f32 -> bf16 convert, two equal-size arrays in one dispatch
__global__ void cvt4_dual(const float* __restrict__ inA, unsigned short* __restrict__ outA,
                          const float* __restrict__ inB, unsigned short* __restrict__ outB) {
  int i = blockIdx.x * 256 + threadIdx.x;
  f32x4 a = ((const f32x4*)inA)[i];
  f32x4 b = ((const f32x4*)inB)[i];
  s16x4 oa, ob;
#pragma unroll
  for (int c = 0; c < 4; ++c) { oa[c] = (short)f2bf(a[c]); ob[c] = (short)f2bf(b[c]); }
  ((s16x4*)outA)[i] = oa;
  ((s16x4*)outB)[i] = ob;
}

// ---------------- weights, GATE-INTERLEAVED rows: output row c <- source row
// sr(c) = g*HID + hid, g=(c>>4)&3, hid=((c>>6)<<4)|(c&15).
// Wihb = bf16(w_ih); W2b = bf16(w_hh - s*w_ih), s=1/(nA-1) (comm fold, alive==1).
__global__ void buildw(const float* __restrict__ w_ih, const float* __restrict__ w_hh,
                       const float* __restrict__ nA,
                       unsigned short* __restrict__ Wihb, unsigned short* __restrict__ W2b) {
  int i = blockIdx.x * 256 + threadIdx.x;  // over GATES*HID/4 = 4M chunks
  float s = 1.0f / (nA[0] - 1.0f);
  int c  = i >> 9;
  int kk = (i & 511) * 4;
  int g   = (c >> 4) & 3;
  int hid = ((c >> 6) << 4) | (c & 15);
  size_t src = ((size_t)g * HID + hid) * HID + kk;
  size_t dst = (size_t)c * HID + kk;
  f32x4 a = *(const f32x4*)&w_ih[src];
  f32x4 b = *(const f32x4*)&w_hh[src];
  s16x4 oa, ob;
#pragma unroll
  for (int e = 0; e < 4; ++e) {
    oa[e] = (short)f2bf(a[e]);
    ob[e] = (short)f2bf(b[e] - s * a[e]);
  }
  *(s16x4*)&Wihb[dst] = oa;
  *(s16x4*)&W2b[dst] = ob;
}

// ---------------- head weights: Whd row 0..63 = act_w, 64 = val_w, 65..127 = 0
__global__ void build_whd(const float* __restrict__ act_w, const float* __restrict__ val_w,
                          unsigned short* __restrict__ whd) {
  int i = blockIdx.x * 256 + threadIdx.x;
  int r = i >> 9;
  int k = (i & 511) * 4;
  f32x4 v = {0.f, 0.f, 0.f, 0.f};
  if (r < 64)       v = *(const f32x4*)&act_w[(size_t)r * HID + k];
  else if (r == 64) v = *(const f32x4*)&val_w[k];
  s16x4 o;
  o[0] = (short)f2bf(v[0]); o[1] = (short)f2bf(v[1]);
  o[2] = (short)f2bf(v[2]); o[3] = (short)f2bf(v[3]);
  *(s16x4*)&whd[(size_t)r * HID + k] = o;
}

// ---------------- combined bias, interleaved: bc[c] = b_ih[sr(c)] + b_hh[sr(c)]
__global__ void biasmix(const float* __restrict__ b_ih, const float* __restrict__ b_hh,
                        float* __restrict__ bc) {
  int i = blockIdx.x * 256 + threadIdx.x;
  if (i < GATES) {
    int g   = (i >> 4) & 3;
    int hid = ((i >> 6) << 4) | (i & 15);
    int src = g * HID + hid;
    bc[i] = b_ih[src] + b_hh[src];
  }
}

// ---------------- n_alive reduction
__global__ void nalive_k(const float* __restrict__ alive, float* __restrict__ nA) {
  __shared__ float red[256];
  float s = 0.f;
  for (int i = threadIdx.x; i < N_AG; i += 256) s += alive[i];
  red[threadIdx.x] = s;
  __syncthreads();
  for (int st = 128; st > 0; st >>= 1) {
    if (threadIdx.x < st) red[threadIdx.x] += red[threadIdx.x + st];
    __syncthreads();
  }
  if (threadIdx.x == 0) nA[0] = red[0];
}

// ---------------- GEMV: q[c] = sum_k Wihb[c][k]*S[k] / (nA-1)  (rows interleaved ->
// q comes out interleaved, matching the fused epilogue's col index)
__global__ __launch_bounds__(256) void gemv_q(const unsigned short* __restrict__ Wihb,
                                              const float* __restrict__ S,
                                              const float* __restrict__ nA,
                                              float* __restrict__ q) {
  __shared__ float Sl[HID];
  int tid = threadIdx.x, lane = tid & 63, wave = tid >> 6;
  for (int k = tid; k < HID; k += 256) Sl[k] = S[k];
  __syncthreads();
  int g = blockIdx.x * 4 + wave;
  const unsigned short* wr = Wihb + (size_t)g * HID;
  float acc = 0.f;
#pragma unroll
  for (int c = 0; c < 4; ++c) {
    int k = c * 512 + lane * 8;
    s16x8 w = *(const s16x8*)&wr[k];
#pragma unroll
    for (int e = 0; e < 8; ++e) acc += bf2f((unsigned short)w[e]) * Sl[k + e];
  }
  for (int off = 32; off; off >>= 1) acc += __shfl_xor(acc, off);
  if (lane == 0) q[g] = acc / (nA[0] - 1.0f);
}

// ---------------- head epilogue: log_softmax over 64 logits + value; 1 wave/agent
__global__ __launch_bounds__(256) void head_ep(const float* __restrict__ zh,
                                               const float* __restrict__ act_b,
                                               const float* __restrict__ val_b,
                                               float* __restrict__ out) {
  int wave = threadIdx.x >> 6, lane = threadIdx.x & 63;
  int row = blockIdx.x * 4 + wave;
  const float* zr = zh + (size_t)row * 128;
  float a = zr[lane] + act_b[lane];
  float m = a;
  for (int off = 32; off; off >>= 1) m = fmaxf(m, __shfl_xor(m, off));
  float ex = expf(a - m), s = ex;
  for (int off = 32; off; off >>= 1) s += __shfl_xor(s, off);
  out[(size_t)row * ACT + lane] = a - m - logf(s);
  if (lane == 0) out[(size_t)N_AG * ACT + row] = zr[64] + val_b[0];
}

extern "C" void kernel_launch(void* const* d_in, const int* in_sizes, int n_in,
                              void* d_out, int out_size, void* d_ws, size_t ws_size,
                              hipStream_t stream) {
  const float* obs   = (const float*)d_in[0];
  const float* alive = (const float*)d_in[1];
  const float* enc_w = (const float*)d_in[2];
  const float* enc_b = (const float*)d_in[3];
  // d_in[4] g_w, d_in[5] g_b unused: gate = ceil(sigmoid(.)) == 1 identically
  const float* w_ih  = (const float*)d_in[6];
  const float* w_hh  = (const float*)d_in[7];
  const float* b_ih  = (const float*)d_in[8];
  const float* b_hh  = (const float*)d_in[9];
  const float* act_w = (const float*)d_in[10];
  const float* act_b = (const float*)d_in[11];
  const float* val_w = (const float*)d_in[12];
  const float* val_b = (const float*)d_in[13];
  float* out = (float*)d_out;

  char* p = (char*)d_ws;
  unsigned short* Wihb = (unsigned short*)p; p += (size_t)GATES * HID * 2;  // 32 MB
  unsigned short* W2b  = (unsigned short*)p; p += (size_t)GATES * HID * 2;  // 32 MB
  unsigned short* E1b  = (unsigned short*)p; p += (size_t)N_AG * GATES * 2; // 32 MB (packed)
  unsigned short* obsb = (unsigned short*)p; p += (size_t)N_AG * OBSD * 2;  // 4 MB
  unsigned short* encb = (unsigned short*)p; p += (size_t)HID * OBSD * 2;   // 4 MB
  unsigned short* eb   = (unsigned short*)p; p += (size_t)N_AG * HID * 2;   // 8 MB
  unsigned short* h0   = (unsigned short*)p; p += (size_t)N_AG * HID * 2;   // 8 MB
  unsigned short* h1   = (unsigned short*)p; p += (size_t)N_AG * HID * 2;   // 8 MB
  unsigned short* Whd  = (unsigned short*)p; p += (size_t)128 * HID * 2;    // 512 KB
  float* cell = (float*)p; p += (size_t)N_AG * HID * 4;                     // 16 MB (packed)
  float* zh   = (float*)p; p += (size_t)N_AG * 128 * 4;                     // 1 MB
  float* bc   = (float*)p; p += GATES * 4;
  float* q    = (float*)p; p += GATES * 4;
  float* S12  = (float*)p; p += 2 * HID * 4;   // S1 (after iter0), S2 (after iter1)
  float* nA   = (float*)p; p += 256;
  float* S1 = S12, *S2 = S12 + HID;

  cvt4_dual<<<(N_AG * OBSD / 4) / 256, 256, 0, stream>>>(obs, obsb, enc_w, encb);
  nalive_k<<<1, 256, 0, stream>>>(alive, nA);
  buildw<<<((size_t)GATES * HID / 4) / 256, 256, 0, stream>>>(w_ih, w_hh, nA, Wihb, W2b);
  build_whd<<<(128 * HID / 4) / 256, 256, 0, stream>>>(act_w, val_w, Whd);
  biasmix<<<GATES / 256, 256, 0, stream>>>(b_ih, b_hh, bc);
  hipMemsetAsync(S12, 0, 2 * HID * 4, stream);
  hipMemsetAsync(zh, 0, (size_t)N_AG * 128 * 4, stream);

  // encoder: eb = bf16(tanh(obs @ enc_w^T + enc_b))
  gemm_bt<1><<<dim3(HID / 128, N_AG / 128), 256, 0, stream>>>(
      obsb, encb, OBSD, OBSD, OBSD, eb, nullptr, HID, enc_b);

  // iter 0 fused: E1 = e @ Wih^T (packed store) + LSTM(c=0) -> cell, h0; S1 += alive*h0
  gemm256<10, 1><<<dim3(GATES / 256, N_AG / 256), 512, 0, stream>>>(
      eb, Wihb, HID, HID, HID, E1b, nullptr, bc, cell, h0, alive, S1);

  // iter 1 fused: z2 = h0 @ W2^T + E1 + q + bc -> LSTM -> cell, h1; S2 += alive*h1
  gemv_q<<<GATES / 4, 256, 0, stream>>>(Wihb, S1, nA, q);
  gemm256<11, 1><<<dim3(GATES / 256, N_AG / 256), 512, 0, stream>>>(
      h0, W2b, HID, HID, HID, E1b, q, bc, cell, h1, alive, S2);

  // iter 2 fused (no S accumulation)
  gemv_q<<<GATES / 4, 256, 0, stream>>>(Wihb, S2, nA, q);
  gemm256<11, 0><<<dim3(GATES / 256, N_AG / 256), 512, 0, stream>>>(
      h1, W2b, HID, HID, HID, E1b, q, bc, cell, h0, alive, nullptr);

  // head: zh(2048x128) = h @ Whd^T, split-K x8 via f32 atomics (128 blocks vs 16)
  gemm_bt<2><<<dim3(1, N_AG / 128, 8), 256, 0, stream>>>(
      h0, Whd, HID / 8, HID, HID, nullptr, zh, 128, nullptr);
  head_ep<<<N_AG / 4, 256, 0, stream>>>(zh, act_b, val_b, out);
}